// Round 1
// baseline (1205.767 us; speedup 1.0000x reference)
//
#include <hip/hip_runtime.h>
#include <math.h>

#define N_NODES 40000
#define N_EDGES 640000
#define D 128
#define BN_EPS 1e-5f

// ---------------- degree / normalization ----------------

__global__ __launch_bounds__(256) void k_deg_init(float* __restrict__ deg) {
    int i = blockIdx.x * 256 + threadIdx.x;
    if (i < N_NODES) deg[i] = 1.0f;   // self-loop
}

__global__ __launch_bounds__(256) void k_deg_count(const int* __restrict__ dst,
                                                   float* __restrict__ deg) {
    int e = blockIdx.x * 256 + threadIdx.x;
    if (e < N_EDGES) atomicAdd(&deg[dst[e]], 1.0f);
}

__global__ __launch_bounds__(256) void k_dinv(float* __restrict__ deg,
                                              float* __restrict__ stats) {
    int i = blockIdx.x * 256 + threadIdx.x;
    if (i < N_NODES) deg[i] = rsqrtf(deg[i]);   // deg >= 1 always
    if (i < 256) stats[i] = 0.0f;               // zero BN sum/sumsq each call
}

// ---------------- h = x @ W ; accum = h * dinv^2 (self-loop) ----------------
// 256 threads: c = tid&31 -> columns 4c..4c+3, g = tid>>5 -> row 0..7 of tile.

__global__ __launch_bounds__(256) void k_gemm(const float* __restrict__ x,
                                              const float* __restrict__ W,
                                              const float* __restrict__ dinv,
                                              float* __restrict__ h,
                                              float* __restrict__ accum) {
    __shared__ float Ws[D * D];          // 64 KB
    __shared__ float xs[8 * D];          // 4 KB
    for (int i = threadIdx.x; i < D * D; i += 256) Ws[i] = W[i];
    int r0 = blockIdx.x * 8;
    ((float4*)xs)[threadIdx.x] =
        ((const float4*)(x + (size_t)r0 * D))[threadIdx.x];  // 8 rows x 128
    __syncthreads();

    int c = threadIdx.x & 31;
    int g = threadIdx.x >> 5;
    const float4* Ws4 = (const float4*)Ws;
    const float* xr = xs + g * D;
    float4 acc = make_float4(0.f, 0.f, 0.f, 0.f);
#pragma unroll 4
    for (int k = 0; k < D; ++k) {
        float xk = xr[k];
        float4 w = Ws4[k * 32 + c];
        acc.x = fmaf(xk, w.x, acc.x);
        acc.y = fmaf(xk, w.y, acc.y);
        acc.z = fmaf(xk, w.z, acc.z);
        acc.w = fmaf(xk, w.w, acc.w);
    }
    int r = r0 + g;
    float di = dinv[r];
    float sl = di * di;
    ((float4*)(h + (size_t)r * D))[c] = acc;
    float4 a2 = make_float4(acc.x * sl, acc.y * sl, acc.z * sl, acc.w * sl);
    ((float4*)(accum + (size_t)r * D))[c] = a2;
}

// ---------------- edge scatter: accum[dst] += h[src] * norm ----------------
// one thread per (edge, 4-column group): 640000*32 threads

__global__ __launch_bounds__(256) void k_scatter(const int* __restrict__ src,
                                                 const int* __restrict__ dst,
                                                 const float* __restrict__ dinv,
                                                 const float* __restrict__ h,
                                                 float* __restrict__ accum) {
    unsigned idx = blockIdx.x * 256u + threadIdx.x;
    int e = idx >> 5;
    int c = idx & 31;
    if (e < N_EDGES) {
        int s = src[e];
        int d = dst[e];
        float nrm = dinv[s] * dinv[d];
        float4 v = ((const float4*)(h + (size_t)s * D))[c];
        float* op = accum + (size_t)d * D + 4 * c;
        atomicAdd(op + 0, v.x * nrm);
        atomicAdd(op + 1, v.y * nrm);
        atomicAdd(op + 2, v.z * nrm);
        atomicAdd(op + 3, v.w * nrm);
    }
}

// ---------------- BN stats: y = relu(accum + b); col sums ----------------

__global__ __launch_bounds__(256) void k_bnstats(const float* __restrict__ accum,
                                                 const float* __restrict__ bvec,
                                                 float* __restrict__ y,
                                                 float* __restrict__ stats) {
    int d = threadIdx.x & 127;
    int g = threadIdx.x >> 7;   // 0 or 1
    float bd = bvec[d];
    float sum = 0.f, sumsq = 0.f;
    for (int r = blockIdx.x * 2 + g; r < N_NODES; r += gridDim.x * 2) {
        float v = accum[(size_t)r * D + d] + bd;
        v = fmaxf(v, 0.f);
        y[(size_t)r * D + d] = v;
        sum += v;
        sumsq = fmaf(v, v, sumsq);
    }
    __shared__ float s1[256], s2[256];
    s1[threadIdx.x] = sum;
    s2[threadIdx.x] = sumsq;
    __syncthreads();
    if (threadIdx.x < 128) {
        atomicAdd(&stats[d],       s1[threadIdx.x] + s1[threadIdx.x + 128]);
        atomicAdd(&stats[128 + d], s2[threadIdx.x] + s2[threadIdx.x + 128]);
    }
}

// ---------------- BN finalize (in place on y) ----------------

__global__ __launch_bounds__(256) void k_bnfinal(float* __restrict__ y,
                                                 const float* __restrict__ stats,
                                                 const float* __restrict__ gamma,
                                                 const float* __restrict__ beta) {
    int idx = blockIdx.x * 256 + threadIdx.x;   // one float4 per thread
    if (idx < N_NODES * 32) {
        int c = idx & 31;
        float4 v = ((const float4*)y)[idx];
        float invN = 1.0f / (float)N_NODES;
        float o[4] = {v.x, v.y, v.z, v.w};
#pragma unroll
        for (int j = 0; j < 4; ++j) {
            int d = 4 * c + j;
            float mean = stats[d] * invN;
            float var = stats[128 + d] * invN - mean * mean;
            float rs = rsqrtf(var + BN_EPS);
            o[j] = (o[j] - mean) * rs * gamma[d] + beta[d];
        }
        ((float4*)y)[idx] = make_float4(o[0], o[1], o[2], o[3]);
    }
}

extern "C" void kernel_launch(void* const* d_in, const int* in_sizes, int n_in,
                              void* d_out, int out_size, void* d_ws, size_t ws_size,
                              hipStream_t stream) {
    const float* x     = (const float*)d_in[0];
    const int*   ei    = (const int*)d_in[1];      // [2, N_EDGES]: row0=src, row1=dst
    const float* W     = (const float*)d_in[2];
    const float* bvec  = (const float*)d_in[3];
    const float* gamma = (const float*)d_in[4];
    const float* beta  = (const float*)d_in[5];
    float* y = (float*)d_out;

    const int* src = ei;
    const int* dst = ei + N_EDGES;

    char* ws = (char*)d_ws;
    float* accum = (float*)ws;                                   // N*D f32 (20.48 MB)
    float* h     = (float*)(ws + (size_t)N_NODES * D * 4);       // N*D f32 (20.48 MB)
    float* dinv  = (float*)(ws + (size_t)2 * N_NODES * D * 4);   // N f32
    float* stats = dinv + N_NODES;                               // 256 f32

    k_deg_init<<<(N_NODES + 255) / 256, 256, 0, stream>>>(dinv);
    k_deg_count<<<(N_EDGES + 255) / 256, 256, 0, stream>>>(dst, dinv);
    k_dinv<<<(N_NODES + 255) / 256, 256, 0, stream>>>(dinv, stats);
    k_gemm<<<N_NODES / 8, 256, 0, stream>>>(x, W, dinv, h, accum);
    k_scatter<<<(N_EDGES * 32) / 256, 256, 0, stream>>>(src, dst, dinv, h, accum);
    k_bnstats<<<256, 256, 0, stream>>>(accum, bvec, y, stats);
    k_bnfinal<<<(N_NODES * 32 + 255) / 256, 256, 0, stream>>>(y, stats, gamma, beta);
}

// Round 2
// 409.676 us; speedup vs baseline: 2.9432x; 2.9432x over previous
//
#include <hip/hip_runtime.h>
#include <math.h>

#define N_NODES 40000
#define N_EDGES 640000
#define D 128
#define BN_EPS 1e-5f

// ---------------- init: zero degree counts + BN stats ----------------

__global__ __launch_bounds__(256) void k_init(int* __restrict__ cnt,
                                              float* __restrict__ stats) {
    int i = blockIdx.x * 256 + threadIdx.x;
    if (i < N_NODES) cnt[i] = 0;
    if (i < 256) stats[i] = 0.0f;
}

__global__ __launch_bounds__(256) void k_count(const int* __restrict__ dst,
                                               int* __restrict__ cnt) {
    int e = blockIdx.x * 256 + threadIdx.x;
    if (e < N_EDGES) atomicAdd(&cnt[dst[e]], 1);
}

__global__ __launch_bounds__(256) void k_dinv(const int* __restrict__ cnt,
                                              float* __restrict__ dinv) {
    int i = blockIdx.x * 256 + threadIdx.x;
    if (i < N_NODES) dinv[i] = rsqrtf((float)(cnt[i] + 1));  // +1 self-loop
}

// ---------------- exclusive scan of cnt -> rowstart, cursor ----------------
// single block, 256 threads, ~157 elements each

__global__ __launch_bounds__(256) void k_scan(const int* __restrict__ cnt,
                                              int* __restrict__ rowstart,
                                              int* __restrict__ cursor) {
    __shared__ int part[256];
    int t = threadIdx.x;
    const int CH = (N_NODES + 255) / 256;
    int lo = t * CH, hi = min(lo + CH, N_NODES);
    int s = 0;
    for (int i = lo; i < hi; ++i) s += cnt[i];
    part[t] = s;
    __syncthreads();
    for (int off = 1; off < 256; off <<= 1) {
        int v = (t >= off) ? part[t - off] : 0;
        __syncthreads();
        if (t >= off) part[t] += v;
        __syncthreads();
    }
    int run = (t == 0) ? 0 : part[t - 1];
    for (int i = lo; i < hi; ++i) {
        rowstart[i] = run;
        cursor[i] = run;
        run += cnt[i];
    }
    if (t == 255) rowstart[N_NODES] = run;  // == N_EDGES
}

__global__ __launch_bounds__(256) void k_fill(const int* __restrict__ src,
                                              const int* __restrict__ dst,
                                              int* __restrict__ cursor,
                                              int* __restrict__ csr) {
    int e = blockIdx.x * 256 + threadIdx.x;
    if (e < N_EDGES) {
        int pos = atomicAdd(&cursor[dst[e]], 1);
        csr[pos] = src[e];
    }
}

// ---------------- h = x @ W ----------------

__global__ __launch_bounds__(256) void k_gemm(const float* __restrict__ x,
                                              const float* __restrict__ W,
                                              float* __restrict__ h) {
    __shared__ float Ws[D * D];          // 64 KB
    __shared__ float xs[8 * D];          // 4 KB
    for (int i = threadIdx.x; i < D * D; i += 256) Ws[i] = W[i];
    int r0 = blockIdx.x * 8;
    ((float4*)xs)[threadIdx.x] =
        ((const float4*)(x + (size_t)r0 * D))[threadIdx.x];
    __syncthreads();

    int c = threadIdx.x & 31;
    int g = threadIdx.x >> 5;
    const float4* Ws4 = (const float4*)Ws;
    const float* xr = xs + g * D;
    float4 acc = make_float4(0.f, 0.f, 0.f, 0.f);
#pragma unroll 4
    for (int k = 0; k < D; ++k) {
        float xk = xr[k];
        float4 w = Ws4[k * 32 + c];
        acc.x = fmaf(xk, w.x, acc.x);
        acc.y = fmaf(xk, w.y, acc.y);
        acc.z = fmaf(xk, w.z, acc.z);
        acc.w = fmaf(xk, w.w, acc.w);
    }
    ((float4*)(h + (size_t)(r0 + g) * D))[c] = acc;
}

// ---------------- gather: y[n] = relu(sum_{s in N(n)} h[s]*nrm + self + b)
//                  + fused BN column sum/sumsq partials ----------------
// 256 threads = 2 nodes x 128 columns

__global__ __launch_bounds__(256) void k_gather(const float* __restrict__ h,
                                                const float* __restrict__ dinv,
                                                const int* __restrict__ rowstart,
                                                const int* __restrict__ csr,
                                                const float* __restrict__ bvec,
                                                float* __restrict__ y,
                                                float* __restrict__ stats) {
    int d = threadIdx.x & 127;
    int half = threadIdx.x >> 7;
    float bd = bvec[d];
    float sum = 0.f, sumsq = 0.f;
    for (int n = blockIdx.x * 2 + half; n < N_NODES; n += gridDim.x * 2) {
        float di = dinv[n];
        float acc = h[(size_t)n * D + d] * di * di;   // self-loop
        int j0 = rowstart[n], j1 = rowstart[n + 1];
        for (int j = j0; j < j1; ++j) {
            int s = csr[j];
            float nrm = dinv[s] * di;
            acc = fmaf(h[(size_t)s * D + d], nrm, acc);
        }
        float v = fmaxf(acc + bd, 0.f);
        y[(size_t)n * D + d] = v;
        sum += v;
        sumsq = fmaf(v, v, sumsq);
    }
    __shared__ float s1[256], s2[256];
    s1[threadIdx.x] = sum;
    s2[threadIdx.x] = sumsq;
    __syncthreads();
    if (threadIdx.x < 128) {
        atomicAdd(&stats[d],       s1[threadIdx.x] + s1[threadIdx.x + 128]);
        atomicAdd(&stats[128 + d], s2[threadIdx.x] + s2[threadIdx.x + 128]);
    }
}

// ---------------- BN finalize (in place on y) ----------------

__global__ __launch_bounds__(256) void k_bnfinal(float* __restrict__ y,
                                                 const float* __restrict__ stats,
                                                 const float* __restrict__ gamma,
                                                 const float* __restrict__ beta) {
    int idx = blockIdx.x * 256 + threadIdx.x;   // one float4 per thread
    if (idx < N_NODES * 32) {
        int c = idx & 31;
        float4 v = ((const float4*)y)[idx];
        float invN = 1.0f / (float)N_NODES;
        float o[4] = {v.x, v.y, v.z, v.w};
#pragma unroll
        for (int j = 0; j < 4; ++j) {
            int dd = 4 * c + j;
            float mean = stats[dd] * invN;
            float var = stats[128 + dd] * invN - mean * mean;
            float rs = rsqrtf(var + BN_EPS);
            o[j] = (o[j] - mean) * rs * gamma[dd] + beta[dd];
        }
        ((float4*)y)[idx] = make_float4(o[0], o[1], o[2], o[3]);
    }
}

extern "C" void kernel_launch(void* const* d_in, const int* in_sizes, int n_in,
                              void* d_out, int out_size, void* d_ws, size_t ws_size,
                              hipStream_t stream) {
    const float* x     = (const float*)d_in[0];
    const int*   ei    = (const int*)d_in[1];      // [2, E]: row0=src, row1=dst
    const float* W     = (const float*)d_in[2];
    const float* bvec  = (const float*)d_in[3];
    const float* gamma = (const float*)d_in[4];
    const float* beta  = (const float*)d_in[5];
    float* y = (float*)d_out;

    const int* src = ei;
    const int* dst = ei + N_EDGES;

    float* h        = (float*)d_ws;                    // N*D
    float* dinv     = h + (size_t)N_NODES * D;         // N
    float* stats    = dinv + N_NODES;                  // 256
    int*   cnt      = (int*)(stats + 256);             // N
    int*   rowstart = cnt + N_NODES;                   // N+1
    int*   cursor   = rowstart + N_NODES + 1;          // N
    int*   csr      = cursor + N_NODES;                // E

    k_init<<<(N_NODES + 255) / 256, 256, 0, stream>>>(cnt, stats);
    k_count<<<(N_EDGES + 255) / 256, 256, 0, stream>>>(dst, cnt);
    k_dinv<<<(N_NODES + 255) / 256, 256, 0, stream>>>(cnt, dinv);
    k_scan<<<1, 256, 0, stream>>>(cnt, rowstart, cursor);
    k_fill<<<(N_EDGES + 255) / 256, 256, 0, stream>>>(src, dst, cursor, csr);
    k_gemm<<<N_NODES / 8, 256, 0, stream>>>(x, W, h);
    k_gather<<<1024, 256, 0, stream>>>(h, dinv, rowstart, csr, bvec, y, stats);
    k_bnfinal<<<(N_NODES * 32 + 255) / 256, 256, 0, stream>>>(y, stats, gamma, beta);
}

// Round 3
// 346.687 us; speedup vs baseline: 3.4780x; 1.1817x over previous
//
#include <hip/hip_runtime.h>
#include <math.h>

#define N_NODES 40000
#define N_EDGES 640000
#define D 128
#define BN_EPS 1e-5f

// ---------------- init: zero degree counts + BN stats ----------------

__global__ __launch_bounds__(256) void k_init(int* __restrict__ cnt,
                                              float* __restrict__ stats) {
    int i = blockIdx.x * 256 + threadIdx.x;
    if (i < N_NODES) cnt[i] = 0;
    if (i < 256) stats[i] = 0.0f;
}

__global__ __launch_bounds__(256) void k_count(const int* __restrict__ dst,
                                               int* __restrict__ cnt) {
    int e = blockIdx.x * 256 + threadIdx.x;
    if (e < N_EDGES) atomicAdd(&cnt[dst[e]], 1);
}

// ---------------- exclusive scan of cnt -> rowstart, cursor, dinv ----------------

__global__ __launch_bounds__(256) void k_scan(const int* __restrict__ cnt,
                                              int* __restrict__ rowstart,
                                              int* __restrict__ cursor,
                                              float* __restrict__ dinv) {
    __shared__ int part[256];
    int t = threadIdx.x;
    const int CH = (N_NODES + 255) / 256;
    int lo = t * CH, hi = min(lo + CH, N_NODES);
    int s = 0;
#pragma unroll 8
    for (int i = lo; i < hi; ++i) s += cnt[i];
    part[t] = s;
    __syncthreads();
    for (int off = 1; off < 256; off <<= 1) {
        int v = (t >= off) ? part[t - off] : 0;
        __syncthreads();
        if (t >= off) part[t] += v;
        __syncthreads();
    }
    int run = (t == 0) ? 0 : part[t - 1];
    for (int i = lo; i < hi; ++i) {
        int c = cnt[i];
        rowstart[i] = run;
        cursor[i] = run;
        dinv[i] = rsqrtf((float)(c + 1));   // +1 self-loop
        run += c;
    }
    if (t == 255) rowstart[N_NODES] = run;  // == N_EDGES
}

__global__ __launch_bounds__(256) void k_fill(const int* __restrict__ src,
                                              const int* __restrict__ dst,
                                              int* __restrict__ cursor,
                                              int* __restrict__ csr) {
    int e = blockIdx.x * 256 + threadIdx.x;
    if (e < N_EDGES) {
        int pos = atomicAdd(&cursor[dst[e]], 1);
        csr[pos] = src[e];
    }
}

// ---------------- h' = (x @ W) * dinv[row] ; 32 rows/block ----------------

__global__ __launch_bounds__(256) void k_gemm(const float* __restrict__ x,
                                              const float* __restrict__ W,
                                              const float* __restrict__ dinv,
                                              float* __restrict__ hp) {
    __shared__ float Ws[D * D];       // 64 KB
    __shared__ float xs[32 * D];      // 16 KB
    for (int i = threadIdx.x; i < D * D / 4; i += 256)
        ((float4*)Ws)[i] = ((const float4*)W)[i];
    int r0 = blockIdx.x * 32;
    for (int i = threadIdx.x; i < 32 * D / 4; i += 256)
        ((float4*)xs)[i] = ((const float4*)(x + (size_t)r0 * D))[i];
    __syncthreads();

    int c = threadIdx.x & 31;   // 4-col group
    int g = threadIdx.x >> 5;   // 4-row group (g*4 .. g*4+3)
    const float4* Ws4 = (const float4*)Ws;
    float4 acc0 = {0,0,0,0}, acc1 = {0,0,0,0}, acc2 = {0,0,0,0}, acc3 = {0,0,0,0};
    const float* xr = xs + g * 4 * D;
    for (int k = 0; k < D; ++k) {
        float4 w = Ws4[k * 32 + c];
        float x0 = xr[k], x1 = xr[D + k], x2 = xr[2 * D + k], x3 = xr[3 * D + k];
        acc0.x = fmaf(x0, w.x, acc0.x); acc0.y = fmaf(x0, w.y, acc0.y);
        acc0.z = fmaf(x0, w.z, acc0.z); acc0.w = fmaf(x0, w.w, acc0.w);
        acc1.x = fmaf(x1, w.x, acc1.x); acc1.y = fmaf(x1, w.y, acc1.y);
        acc1.z = fmaf(x1, w.z, acc1.z); acc1.w = fmaf(x1, w.w, acc1.w);
        acc2.x = fmaf(x2, w.x, acc2.x); acc2.y = fmaf(x2, w.y, acc2.y);
        acc2.z = fmaf(x2, w.z, acc2.z); acc2.w = fmaf(x2, w.w, acc2.w);
        acc3.x = fmaf(x3, w.x, acc3.x); acc3.y = fmaf(x3, w.y, acc3.y);
        acc3.z = fmaf(x3, w.z, acc3.z); acc3.w = fmaf(x3, w.w, acc3.w);
    }
    float4 a[4] = {acc0, acc1, acc2, acc3};
#pragma unroll
    for (int rr = 0; rr < 4; ++rr) {
        int r = r0 + g * 4 + rr;
        float sc = dinv[r];
        float4 v = a[rr];
        v.x *= sc; v.y *= sc; v.z *= sc; v.w *= sc;
        ((float4*)(hp + (size_t)r * D))[c] = v;
    }
}

// ---------------- gather: y[n] = relu((h'[n] + sum h'[s]) * dinv[n] + b)
//                  + fused BN column partials. 8 nodes/block, float4 lanes.

__global__ __launch_bounds__(256) void k_gather(const float* __restrict__ hp,
                                                const float* __restrict__ dinv,
                                                const int* __restrict__ rowstart,
                                                const int* __restrict__ csr,
                                                const float* __restrict__ bvec,
                                                float* __restrict__ y,
                                                float* __restrict__ stats) {
    const float4* h4 = (const float4*)hp;
    float4* y4 = (float4*)y;
    int c = threadIdx.x & 31;   // float4 column group
    int g = threadIdx.x >> 5;   // node within group of 8
    float4 b4 = ((const float4*)bvec)[c];
    float4 sum = {0,0,0,0}, ssq = {0,0,0,0};

    for (int n0 = blockIdx.x * 8; n0 < N_NODES; n0 += gridDim.x * 8) {
        int n = n0 + g;
        float4 acc = h4[(size_t)n * 32 + c];   // self-loop term
        int j = rowstart[n], j1 = rowstart[n + 1];
        for (; j + 3 < j1; j += 4) {
            int s0 = csr[j], s1 = csr[j + 1], s2 = csr[j + 2], s3 = csr[j + 3];
            float4 v0 = h4[(size_t)s0 * 32 + c];
            float4 v1 = h4[(size_t)s1 * 32 + c];
            float4 v2 = h4[(size_t)s2 * 32 + c];
            float4 v3 = h4[(size_t)s3 * 32 + c];
            acc.x += (v0.x + v1.x) + (v2.x + v3.x);
            acc.y += (v0.y + v1.y) + (v2.y + v3.y);
            acc.z += (v0.z + v1.z) + (v2.z + v3.z);
            acc.w += (v0.w + v1.w) + (v2.w + v3.w);
        }
        for (; j < j1; ++j) {
            int s = csr[j];
            float4 v = h4[(size_t)s * 32 + c];
            acc.x += v.x; acc.y += v.y; acc.z += v.z; acc.w += v.w;
        }
        float di = dinv[n];
        float4 o;
        o.x = fmaxf(fmaf(acc.x, di, b4.x), 0.f);
        o.y = fmaxf(fmaf(acc.y, di, b4.y), 0.f);
        o.z = fmaxf(fmaf(acc.z, di, b4.z), 0.f);
        o.w = fmaxf(fmaf(acc.w, di, b4.w), 0.f);
        y4[(size_t)n * 32 + c] = o;
        sum.x += o.x; sum.y += o.y; sum.z += o.z; sum.w += o.w;
        ssq.x = fmaf(o.x, o.x, ssq.x); ssq.y = fmaf(o.y, o.y, ssq.y);
        ssq.z = fmaf(o.z, o.z, ssq.z); ssq.w = fmaf(o.w, o.w, ssq.w);
    }

    __shared__ float4 s1m[256], s2m[256];
    s1m[threadIdx.x] = sum;
    s2m[threadIdx.x] = ssq;
    __syncthreads();
    if (threadIdx.x < 32) {
        float4 a = s1m[threadIdx.x], b = s2m[threadIdx.x];
#pragma unroll
        for (int g2 = 1; g2 < 8; ++g2) {
            float4 p = s1m[g2 * 32 + threadIdx.x], q = s2m[g2 * 32 + threadIdx.x];
            a.x += p.x; a.y += p.y; a.z += p.z; a.w += p.w;
            b.x += q.x; b.y += q.y; b.z += q.z; b.w += q.w;
        }
        int d0 = 4 * threadIdx.x;
        atomicAdd(&stats[d0 + 0], a.x); atomicAdd(&stats[d0 + 1], a.y);
        atomicAdd(&stats[d0 + 2], a.z); atomicAdd(&stats[d0 + 3], a.w);
        atomicAdd(&stats[128 + d0 + 0], b.x); atomicAdd(&stats[128 + d0 + 1], b.y);
        atomicAdd(&stats[128 + d0 + 2], b.z); atomicAdd(&stats[128 + d0 + 3], b.w);
    }
}

// ---------------- BN finalize (in place on y) ----------------

__global__ __launch_bounds__(256) void k_bnfinal(float* __restrict__ y,
                                                 const float* __restrict__ stats,
                                                 const float* __restrict__ gamma,
                                                 const float* __restrict__ beta) {
    int idx = blockIdx.x * 256 + threadIdx.x;   // one float4 per thread
    if (idx < N_NODES * 32) {
        int c = idx & 31;
        float4 v = ((const float4*)y)[idx];
        float invN = 1.0f / (float)N_NODES;
        float o[4] = {v.x, v.y, v.z, v.w};
#pragma unroll
        for (int j = 0; j < 4; ++j) {
            int dd = 4 * c + j;
            float mean = stats[dd] * invN;
            float var = stats[128 + dd] * invN - mean * mean;
            float rs = rsqrtf(var + BN_EPS);
            o[j] = (o[j] - mean) * rs * gamma[dd] + beta[dd];
        }
        ((float4*)y)[idx] = make_float4(o[0], o[1], o[2], o[3]);
    }
}

extern "C" void kernel_launch(void* const* d_in, const int* in_sizes, int n_in,
                              void* d_out, int out_size, void* d_ws, size_t ws_size,
                              hipStream_t stream) {
    const float* x     = (const float*)d_in[0];
    const int*   ei    = (const int*)d_in[1];      // [2, E]: row0=src, row1=dst
    const float* W     = (const float*)d_in[2];
    const float* bvec  = (const float*)d_in[3];
    const float* gamma = (const float*)d_in[4];
    const float* beta  = (const float*)d_in[5];
    float* y = (float*)d_out;

    const int* src = ei;
    const int* dst = ei + N_EDGES;

    float* hp       = (float*)d_ws;                    // N*D
    float* dinv     = hp + (size_t)N_NODES * D;        // N
    float* stats    = dinv + N_NODES;                  // 256
    int*   cnt      = (int*)(stats + 256);             // N
    int*   rowstart = cnt + N_NODES;                   // N+1
    int*   cursor   = rowstart + N_NODES + 1;          // N
    int*   csr      = cursor + N_NODES;                // E

    k_init<<<(N_NODES + 255) / 256, 256, 0, stream>>>(cnt, stats);
    k_count<<<(N_EDGES + 255) / 256, 256, 0, stream>>>(dst, cnt);
    k_scan<<<1, 256, 0, stream>>>(cnt, rowstart, cursor, dinv);
    k_fill<<<(N_EDGES + 255) / 256, 256, 0, stream>>>(src, dst, cursor, csr);
    k_gemm<<<N_NODES / 32, 256, 0, stream>>>(x, W, dinv, hp);
    k_gather<<<1024, 256, 0, stream>>>(hp, dinv, rowstart, csr, bvec, y, stats);
    k_bnfinal<<<(N_NODES * 32 + 255) / 256, 256, 0, stream>>>(y, stats, gamma, beta);
}

// Round 4
// 326.762 us; speedup vs baseline: 3.6901x; 1.0610x over previous
//
#include <hip/hip_runtime.h>
#include <math.h>

#define N_NODES 40000
#define N_EDGES 640000
#define D 128
#define BN_EPS 1e-5f
#define SCAN_BLOCKS ((N_NODES + 255) / 256)   // 157

// ---------------- init: zero degree counts + BN stats ----------------

__global__ __launch_bounds__(256) void k_init(int* __restrict__ cnt,
                                              float* __restrict__ stats) {
    int i = blockIdx.x * 256 + threadIdx.x;
    if (i < N_NODES) cnt[i] = 0;
    if (i < 256) stats[i] = 0.0f;
}

__global__ __launch_bounds__(256) void k_count(const int* __restrict__ dst,
                                               int* __restrict__ cnt) {
    int e = blockIdx.x * 256 + threadIdx.x;
    if (e < N_EDGES) atomicAdd(&cnt[dst[e]], 1);
}

// ---------------- parallel scan chain ----------------
// A: per-block sums of cnt

__global__ __launch_bounds__(256) void k_scanpart(const int* __restrict__ cnt,
                                                  int* __restrict__ bsum) {
    __shared__ int red[256];
    int i = blockIdx.x * 256 + threadIdx.x;
    red[threadIdx.x] = (i < N_NODES) ? cnt[i] : 0;
    __syncthreads();
    for (int off = 128; off > 0; off >>= 1) {
        if (threadIdx.x < off) red[threadIdx.x] += red[threadIdx.x + off];
        __syncthreads();
    }
    if (threadIdx.x == 0) bsum[blockIdx.x] = red[0];
}

// B: exclusive scan of the 157 block sums (1 block)

__global__ __launch_bounds__(256) void k_scantop(const int* __restrict__ bsum,
                                                 int* __restrict__ bbase) {
    __shared__ int part[256];
    int t = threadIdx.x;
    int v = (t < SCAN_BLOCKS) ? bsum[t] : 0;
    part[t] = v;
    __syncthreads();
    for (int off = 1; off < 256; off <<= 1) {
        int p = (t >= off) ? part[t - off] : 0;
        __syncthreads();
        part[t] += p;
        __syncthreads();
    }
    bbase[t] = part[t] - v;   // exclusive
}

// C: per-block in-block scan + fill rowstart/cursor/dinv

__global__ __launch_bounds__(256) void k_scanfill(const int* __restrict__ cnt,
                                                  const int* __restrict__ bbase,
                                                  int* __restrict__ rowstart,
                                                  int* __restrict__ cursor,
                                                  float* __restrict__ dinv) {
    __shared__ int part[256];
    int t = threadIdx.x;
    int i = blockIdx.x * 256 + t;
    int c = (i < N_NODES) ? cnt[i] : 0;
    part[t] = c;
    __syncthreads();
    for (int off = 1; off < 256; off <<= 1) {
        int p = (t >= off) ? part[t - off] : 0;
        __syncthreads();
        part[t] += p;
        __syncthreads();
    }
    int rs = bbase[blockIdx.x] + part[t] - c;   // exclusive prefix
    if (i < N_NODES) {
        rowstart[i] = rs;
        cursor[i] = rs;
        dinv[i] = rsqrtf((float)(c + 1));       // +1 self-loop
        if (i == N_NODES - 1) rowstart[N_NODES] = rs + c;   // == N_EDGES
    }
}

__global__ __launch_bounds__(256) void k_fill(const int* __restrict__ src,
                                              const int* __restrict__ dst,
                                              int* __restrict__ cursor,
                                              int* __restrict__ csr) {
    int e = blockIdx.x * 256 + threadIdx.x;
    if (e < N_EDGES) {
        int pos = atomicAdd(&cursor[dst[e]], 1);
        csr[pos] = src[e];
    }
}

// ---------------- h' = (x @ W) * dinv[row] ; 32 rows/block ----------------

__global__ __launch_bounds__(256) void k_gemm(const float* __restrict__ x,
                                              const float* __restrict__ W,
                                              const float* __restrict__ dinv,
                                              float* __restrict__ hp) {
    __shared__ float Ws[D * D];       // 64 KB
    __shared__ float xs[32 * D];      // 16 KB
    for (int i = threadIdx.x; i < D * D / 4; i += 256)
        ((float4*)Ws)[i] = ((const float4*)W)[i];
    int r0 = blockIdx.x * 32;
    for (int i = threadIdx.x; i < 32 * D / 4; i += 256)
        ((float4*)xs)[i] = ((const float4*)(x + (size_t)r0 * D))[i];
    __syncthreads();

    int c = threadIdx.x & 31;   // 4-col group
    int g = threadIdx.x >> 5;   // 4-row group
    const float4* Ws4 = (const float4*)Ws;
    float4 acc0 = {0,0,0,0}, acc1 = {0,0,0,0}, acc2 = {0,0,0,0}, acc3 = {0,0,0,0};
    const float* xr = xs + g * 4 * D;
    for (int k = 0; k < D; ++k) {
        float4 w = Ws4[k * 32 + c];
        float x0 = xr[k], x1 = xr[D + k], x2 = xr[2 * D + k], x3 = xr[3 * D + k];
        acc0.x = fmaf(x0, w.x, acc0.x); acc0.y = fmaf(x0, w.y, acc0.y);
        acc0.z = fmaf(x0, w.z, acc0.z); acc0.w = fmaf(x0, w.w, acc0.w);
        acc1.x = fmaf(x1, w.x, acc1.x); acc1.y = fmaf(x1, w.y, acc1.y);
        acc1.z = fmaf(x1, w.z, acc1.z); acc1.w = fmaf(x1, w.w, acc1.w);
        acc2.x = fmaf(x2, w.x, acc2.x); acc2.y = fmaf(x2, w.y, acc2.y);
        acc2.z = fmaf(x2, w.z, acc2.z); acc2.w = fmaf(x2, w.w, acc2.w);
        acc3.x = fmaf(x3, w.x, acc3.x); acc3.y = fmaf(x3, w.y, acc3.y);
        acc3.z = fmaf(x3, w.z, acc3.z); acc3.w = fmaf(x3, w.w, acc3.w);
    }
    float4 a[4] = {acc0, acc1, acc2, acc3};
#pragma unroll
    for (int rr = 0; rr < 4; ++rr) {
        int r = r0 + g * 4 + rr;
        float sc = dinv[r];
        float4 v = a[rr];
        v.x *= sc; v.y *= sc; v.z *= sc; v.w *= sc;
        ((float4*)(hp + (size_t)r * D))[c] = v;
    }
}

// ---------------- gather: y[n] = relu((h'[n] + sum h'[s]) * dinv[n] + b)
//                  + fused BN column partials. 8 nodes/block, unroll 8.

__global__ __launch_bounds__(256) void k_gather(const float* __restrict__ hp,
                                                const float* __restrict__ dinv,
                                                const int* __restrict__ rowstart,
                                                const int* __restrict__ csr,
                                                const float* __restrict__ bvec,
                                                float* __restrict__ y,
                                                float* __restrict__ stats) {
    const float4* h4 = (const float4*)hp;
    float4* y4 = (float4*)y;
    int c = threadIdx.x & 31;   // float4 column group
    int g = threadIdx.x >> 5;   // node within group of 8
    float4 b4 = ((const float4*)bvec)[c];
    float4 sum = {0,0,0,0}, ssq = {0,0,0,0};

    const int NG = N_NODES / 8;   // 5000 node groups
    for (int grp = blockIdx.x; grp < NG; grp += gridDim.x) {
        int n = grp * 8 + g;
        float4 acc = h4[(size_t)n * 32 + c];   // self-loop term
        int j = rowstart[n], j1 = rowstart[n + 1];
        for (; j + 8 <= j1; j += 8) {
            int s0 = csr[j + 0], s1 = csr[j + 1], s2 = csr[j + 2], s3 = csr[j + 3];
            int s4 = csr[j + 4], s5 = csr[j + 5], s6 = csr[j + 6], s7 = csr[j + 7];
            float4 v0 = h4[(size_t)s0 * 32 + c];
            float4 v1 = h4[(size_t)s1 * 32 + c];
            float4 v2 = h4[(size_t)s2 * 32 + c];
            float4 v3 = h4[(size_t)s3 * 32 + c];
            float4 v4 = h4[(size_t)s4 * 32 + c];
            float4 v5 = h4[(size_t)s5 * 32 + c];
            float4 v6 = h4[(size_t)s6 * 32 + c];
            float4 v7 = h4[(size_t)s7 * 32 + c];
            acc.x += ((v0.x + v1.x) + (v2.x + v3.x)) + ((v4.x + v5.x) + (v6.x + v7.x));
            acc.y += ((v0.y + v1.y) + (v2.y + v3.y)) + ((v4.y + v5.y) + (v6.y + v7.y));
            acc.z += ((v0.z + v1.z) + (v2.z + v3.z)) + ((v4.z + v5.z) + (v6.z + v7.z));
            acc.w += ((v0.w + v1.w) + (v2.w + v3.w)) + ((v4.w + v5.w) + (v6.w + v7.w));
        }
        for (; j < j1; ++j) {
            int s = csr[j];
            float4 v = h4[(size_t)s * 32 + c];
            acc.x += v.x; acc.y += v.y; acc.z += v.z; acc.w += v.w;
        }
        float di = dinv[n];
        float4 o;
        o.x = fmaxf(fmaf(acc.x, di, b4.x), 0.f);
        o.y = fmaxf(fmaf(acc.y, di, b4.y), 0.f);
        o.z = fmaxf(fmaf(acc.z, di, b4.z), 0.f);
        o.w = fmaxf(fmaf(acc.w, di, b4.w), 0.f);
        y4[(size_t)n * 32 + c] = o;
        sum.x += o.x; sum.y += o.y; sum.z += o.z; sum.w += o.w;
        ssq.x = fmaf(o.x, o.x, ssq.x); ssq.y = fmaf(o.y, o.y, ssq.y);
        ssq.z = fmaf(o.z, o.z, ssq.z); ssq.w = fmaf(o.w, o.w, ssq.w);
    }

    __shared__ float4 s1m[256], s2m[256];
    s1m[threadIdx.x] = sum;
    s2m[threadIdx.x] = ssq;
    __syncthreads();
    if (threadIdx.x < 32) {
        float4 a = s1m[threadIdx.x], b = s2m[threadIdx.x];
#pragma unroll
        for (int g2 = 1; g2 < 8; ++g2) {
            float4 p = s1m[g2 * 32 + threadIdx.x], q = s2m[g2 * 32 + threadIdx.x];
            a.x += p.x; a.y += p.y; a.z += p.z; a.w += p.w;
            b.x += q.x; b.y += q.y; b.z += q.z; b.w += q.w;
        }
        int d0 = 4 * threadIdx.x;
        atomicAdd(&stats[d0 + 0], a.x); atomicAdd(&stats[d0 + 1], a.y);
        atomicAdd(&stats[d0 + 2], a.z); atomicAdd(&stats[d0 + 3], a.w);
        atomicAdd(&stats[128 + d0 + 0], b.x); atomicAdd(&stats[128 + d0 + 1], b.y);
        atomicAdd(&stats[128 + d0 + 2], b.z); atomicAdd(&stats[128 + d0 + 3], b.w);
    }
}

// ---------------- BN finalize (in place on y) ----------------

__global__ __launch_bounds__(256) void k_bnfinal(float* __restrict__ y,
                                                 const float* __restrict__ stats,
                                                 const float* __restrict__ gamma,
                                                 const float* __restrict__ beta) {
    int idx = blockIdx.x * 256 + threadIdx.x;   // one float4 per thread
    if (idx < N_NODES * 32) {
        int c = idx & 31;
        float4 v = ((const float4*)y)[idx];
        float invN = 1.0f / (float)N_NODES;
        float o[4] = {v.x, v.y, v.z, v.w};
#pragma unroll
        for (int j = 0; j < 4; ++j) {
            int dd = 4 * c + j;
            float mean = stats[dd] * invN;
            float var = stats[128 + dd] * invN - mean * mean;
            float rs = rsqrtf(var + BN_EPS);
            o[j] = (o[j] - mean) * rs * gamma[dd] + beta[dd];
        }
        ((float4*)y)[idx] = make_float4(o[0], o[1], o[2], o[3]);
    }
}

extern "C" void kernel_launch(void* const* d_in, const int* in_sizes, int n_in,
                              void* d_out, int out_size, void* d_ws, size_t ws_size,
                              hipStream_t stream) {
    const float* x     = (const float*)d_in[0];
    const int*   ei    = (const int*)d_in[1];      // [2, E]: row0=src, row1=dst
    const float* W     = (const float*)d_in[2];
    const float* bvec  = (const float*)d_in[3];
    const float* gamma = (const float*)d_in[4];
    const float* beta  = (const float*)d_in[5];
    float* y = (float*)d_out;

    const int* src = ei;
    const int* dst = ei + N_EDGES;

    float* hp       = (float*)d_ws;                    // N*D
    float* dinv     = hp + (size_t)N_NODES * D;        // N
    float* stats    = dinv + N_NODES;                  // 256
    int*   cnt      = (int*)(stats + 256);             // N
    int*   rowstart = cnt + N_NODES;                   // N+1
    int*   cursor   = rowstart + N_NODES + 1;          // N
    int*   csr      = cursor + N_NODES;                // E
    int*   bsum     = csr + N_EDGES;                   // 256
    int*   bbase    = bsum + 256;                      // 256

    k_init<<<SCAN_BLOCKS, 256, 0, stream>>>(cnt, stats);
    k_count<<<(N_EDGES + 255) / 256, 256, 0, stream>>>(dst, cnt);
    k_scanpart<<<SCAN_BLOCKS, 256, 0, stream>>>(cnt, bsum);
    k_scantop<<<1, 256, 0, stream>>>(bsum, bbase);
    k_scanfill<<<SCAN_BLOCKS, 256, 0, stream>>>(cnt, bbase, rowstart, cursor, dinv);
    k_fill<<<(N_EDGES + 255) / 256, 256, 0, stream>>>(src, dst, cursor, csr);
    k_gemm<<<N_NODES / 32, 256, 0, stream>>>(x, W, dinv, hp);
    k_gather<<<1792, 256, 0, stream>>>(hp, dinv, rowstart, csr, bvec, y, stats);
    k_bnfinal<<<(N_NODES * 32 + 255) / 256, 256, 0, stream>>>(y, stats, gamma, beta);
}

// Round 5
// 307.994 us; speedup vs baseline: 3.9149x; 1.0609x over previous
//
#include <hip/hip_runtime.h>
#include <math.h>

#define N_NODES 40000
#define N_EDGES 640000
#define D 128
#define BN_EPS 1e-5f
#define SCAN_BLOCKS ((N_NODES + 255) / 256)   // 157

// ---------------- init: zero degree counts + BN stats + zero row ----------------

__global__ __launch_bounds__(256) void k_init(int* __restrict__ cnt,
                                              float* __restrict__ stats,
                                              float* __restrict__ zrow) {
    int i = blockIdx.x * 256 + threadIdx.x;
    if (i < N_NODES) cnt[i] = 0;
    if (i < 256) stats[i] = 0.0f;
    if (i < D) zrow[i] = 0.0f;     // hp row N_NODES: dummy target for padded lanes
}

__global__ __launch_bounds__(256) void k_count(const int* __restrict__ dst,
                                               int* __restrict__ cnt) {
    int e = blockIdx.x * 256 + threadIdx.x;
    if (e < N_EDGES) atomicAdd(&cnt[dst[e]], 1);
}

// ---------------- parallel scan chain ----------------

__global__ __launch_bounds__(256) void k_scanpart(const int* __restrict__ cnt,
                                                  int* __restrict__ bsum) {
    __shared__ int red[256];
    int i = blockIdx.x * 256 + threadIdx.x;
    red[threadIdx.x] = (i < N_NODES) ? cnt[i] : 0;
    __syncthreads();
    for (int off = 128; off > 0; off >>= 1) {
        if (threadIdx.x < off) red[threadIdx.x] += red[threadIdx.x + off];
        __syncthreads();
    }
    if (threadIdx.x == 0) bsum[blockIdx.x] = red[0];
}

__global__ __launch_bounds__(256) void k_scantop(const int* __restrict__ bsum,
                                                 int* __restrict__ bbase) {
    __shared__ int part[256];
    int t = threadIdx.x;
    int v = (t < SCAN_BLOCKS) ? bsum[t] : 0;
    part[t] = v;
    __syncthreads();
    for (int off = 1; off < 256; off <<= 1) {
        int p = (t >= off) ? part[t - off] : 0;
        __syncthreads();
        part[t] += p;
        __syncthreads();
    }
    bbase[t] = part[t] - v;   // exclusive
}

__global__ __launch_bounds__(256) void k_scanfill(const int* __restrict__ cnt,
                                                  const int* __restrict__ bbase,
                                                  int* __restrict__ rowstart,
                                                  int* __restrict__ cursor,
                                                  float* __restrict__ dinv) {
    __shared__ int part[256];
    int t = threadIdx.x;
    int i = blockIdx.x * 256 + t;
    int c = (i < N_NODES) ? cnt[i] : 0;
    part[t] = c;
    __syncthreads();
    for (int off = 1; off < 256; off <<= 1) {
        int p = (t >= off) ? part[t - off] : 0;
        __syncthreads();
        part[t] += p;
        __syncthreads();
    }
    int rs = bbase[blockIdx.x] + part[t] - c;   // exclusive prefix
    if (i < N_NODES) {
        rowstart[i] = rs;
        cursor[i] = rs;
        dinv[i] = rsqrtf((float)(c + 1));       // +1 self-loop
        if (i == N_NODES - 1) rowstart[N_NODES] = rs + c;   // == N_EDGES
    }
}

__global__ __launch_bounds__(256) void k_fill(const int* __restrict__ src,
                                              const int* __restrict__ dst,
                                              int* __restrict__ cursor,
                                              int* __restrict__ csr) {
    int e = blockIdx.x * 256 + threadIdx.x;
    if (e < N_EDGES) {
        int pos = atomicAdd(&cursor[dst[e]], 1);
        csr[pos] = src[e];
    }
}

// ---------------- h' = (x @ W) * dinv[row] ; 32 rows/block ----------------

__global__ __launch_bounds__(256) void k_gemm(const float* __restrict__ x,
                                              const float* __restrict__ W,
                                              const float* __restrict__ dinv,
                                              float* __restrict__ hp) {
    __shared__ float Ws[D * D];       // 64 KB
    __shared__ float xs[32 * D];      // 16 KB
    for (int i = threadIdx.x; i < D * D / 4; i += 256)
        ((float4*)Ws)[i] = ((const float4*)W)[i];
    int r0 = blockIdx.x * 32;
    for (int i = threadIdx.x; i < 32 * D / 4; i += 256)
        ((float4*)xs)[i] = ((const float4*)(x + (size_t)r0 * D))[i];
    __syncthreads();

    int c = threadIdx.x & 31;   // 4-col group
    int g = threadIdx.x >> 5;   // 4-row group
    const float4* Ws4 = (const float4*)Ws;
    float4 acc0 = {0,0,0,0}, acc1 = {0,0,0,0}, acc2 = {0,0,0,0}, acc3 = {0,0,0,0};
    const float* xr = xs + g * 4 * D;
    for (int k = 0; k < D; ++k) {
        float4 w = Ws4[k * 32 + c];
        float x0 = xr[k], x1 = xr[D + k], x2 = xr[2 * D + k], x3 = xr[3 * D + k];
        acc0.x = fmaf(x0, w.x, acc0.x); acc0.y = fmaf(x0, w.y, acc0.y);
        acc0.z = fmaf(x0, w.z, acc0.z); acc0.w = fmaf(x0, w.w, acc0.w);
        acc1.x = fmaf(x1, w.x, acc1.x); acc1.y = fmaf(x1, w.y, acc1.y);
        acc1.z = fmaf(x1, w.z, acc1.z); acc1.w = fmaf(x1, w.w, acc1.w);
        acc2.x = fmaf(x2, w.x, acc2.x); acc2.y = fmaf(x2, w.y, acc2.y);
        acc2.z = fmaf(x2, w.z, acc2.z); acc2.w = fmaf(x2, w.w, acc2.w);
        acc3.x = fmaf(x3, w.x, acc3.x); acc3.y = fmaf(x3, w.y, acc3.y);
        acc3.z = fmaf(x3, w.z, acc3.z); acc3.w = fmaf(x3, w.w, acc3.w);
    }
    float4 a[4] = {acc0, acc1, acc2, acc3};
#pragma unroll
    for (int rr = 0; rr < 4; ++rr) {
        int r = r0 + g * 4 + rr;
        float sc = dinv[r];
        float4 v = a[rr];
        v.x *= sc; v.y *= sc; v.z *= sc; v.w *= sc;
        ((float4*)(hp + (size_t)r * D))[c] = v;
    }
}

// ---------------- gather: y[n] = relu((h'[n] + sum h'[s]) * dinv[n] + b)
//       predicated 8-wide bursts (no serial remainder); dummy -> zero row

__global__ __launch_bounds__(256) void k_gather(const float* __restrict__ hp,
                                                const float* __restrict__ dinv,
                                                const int* __restrict__ rowstart,
                                                const int* __restrict__ csr,
                                                const float* __restrict__ bvec,
                                                float* __restrict__ y,
                                                float* __restrict__ stats) {
    const float4* h4 = (const float4*)hp;
    float4* y4 = (float4*)y;
    int c = threadIdx.x & 31;   // float4 column group
    int g = threadIdx.x >> 5;   // node within group of 8
    float4 b4 = ((const float4*)bvec)[c];
    float4 sum = {0,0,0,0}, ssq = {0,0,0,0};

    const int NG = N_NODES / 8;   // 5000 node groups; 1667 blocks x 3
    for (int grp = blockIdx.x; grp < NG; grp += gridDim.x) {
        int n = grp * 8 + g;
        float4 acc = h4[(size_t)n * 32 + c];   // self-loop term
        int j0 = rowstart[n], j1 = rowstart[n + 1];
        for (int j = j0; j < j1; j += 8) {
            int idx[8];
#pragma unroll
            for (int k = 0; k < 8; ++k) {
                int jj = j + k;
                int jc = min(jj, j1 - 1);          // in-bounds csr read
                int s = csr[jc];
                idx[k] = (jj < j1) ? s : N_NODES;  // dummy -> zero row (L1-hot)
            }
            float4 v0 = h4[(size_t)idx[0] * 32 + c];
            float4 v1 = h4[(size_t)idx[1] * 32 + c];
            float4 v2 = h4[(size_t)idx[2] * 32 + c];
            float4 v3 = h4[(size_t)idx[3] * 32 + c];
            float4 v4 = h4[(size_t)idx[4] * 32 + c];
            float4 v5 = h4[(size_t)idx[5] * 32 + c];
            float4 v6 = h4[(size_t)idx[6] * 32 + c];
            float4 v7 = h4[(size_t)idx[7] * 32 + c];
            acc.x += ((v0.x + v1.x) + (v2.x + v3.x)) + ((v4.x + v5.x) + (v6.x + v7.x));
            acc.y += ((v0.y + v1.y) + (v2.y + v3.y)) + ((v4.y + v5.y) + (v6.y + v7.y));
            acc.z += ((v0.z + v1.z) + (v2.z + v3.z)) + ((v4.z + v5.z) + (v6.z + v7.z));
            acc.w += ((v0.w + v1.w) + (v2.w + v3.w)) + ((v4.w + v5.w) + (v6.w + v7.w));
        }
        float di = dinv[n];
        float4 o;
        o.x = fmaxf(fmaf(acc.x, di, b4.x), 0.f);
        o.y = fmaxf(fmaf(acc.y, di, b4.y), 0.f);
        o.z = fmaxf(fmaf(acc.z, di, b4.z), 0.f);
        o.w = fmaxf(fmaf(acc.w, di, b4.w), 0.f);
        y4[(size_t)n * 32 + c] = o;
        sum.x += o.x; sum.y += o.y; sum.z += o.z; sum.w += o.w;
        ssq.x = fmaf(o.x, o.x, ssq.x); ssq.y = fmaf(o.y, o.y, ssq.y);
        ssq.z = fmaf(o.z, o.z, ssq.z); ssq.w = fmaf(o.w, o.w, ssq.w);
    }

    __shared__ float4 s1m[256], s2m[256];
    s1m[threadIdx.x] = sum;
    s2m[threadIdx.x] = ssq;
    __syncthreads();
    if (threadIdx.x < 32) {
        float4 a = s1m[threadIdx.x], b = s2m[threadIdx.x];
#pragma unroll
        for (int g2 = 1; g2 < 8; ++g2) {
            float4 p = s1m[g2 * 32 + threadIdx.x], q = s2m[g2 * 32 + threadIdx.x];
            a.x += p.x; a.y += p.y; a.z += p.z; a.w += p.w;
            b.x += q.x; b.y += q.y; b.z += q.z; b.w += q.w;
        }
        int d0 = 4 * threadIdx.x;
        atomicAdd(&stats[d0 + 0], a.x); atomicAdd(&stats[d0 + 1], a.y);
        atomicAdd(&stats[d0 + 2], a.z); atomicAdd(&stats[d0 + 3], a.w);
        atomicAdd(&stats[128 + d0 + 0], b.x); atomicAdd(&stats[128 + d0 + 1], b.y);
        atomicAdd(&stats[128 + d0 + 2], b.z); atomicAdd(&stats[128 + d0 + 3], b.w);
    }
}

// ---------------- BN finalize (in place on y) ----------------

__global__ __launch_bounds__(256) void k_bnfinal(float* __restrict__ y,
                                                 const float* __restrict__ stats,
                                                 const float* __restrict__ gamma,
                                                 const float* __restrict__ beta) {
    int idx = blockIdx.x * 256 + threadIdx.x;   // one float4 per thread
    if (idx < N_NODES * 32) {
        int c = idx & 31;
        float4 v = ((const float4*)y)[idx];
        float invN = 1.0f / (float)N_NODES;
        float o[4] = {v.x, v.y, v.z, v.w};
#pragma unroll
        for (int j = 0; j < 4; ++j) {
            int dd = 4 * c + j;
            float mean = stats[dd] * invN;
            float var = stats[128 + dd] * invN - mean * mean;
            float rs = rsqrtf(var + BN_EPS);
            o[j] = (o[j] - mean) * rs * gamma[dd] + beta[dd];
        }
        ((float4*)y)[idx] = make_float4(o[0], o[1], o[2], o[3]);
    }
}

extern "C" void kernel_launch(void* const* d_in, const int* in_sizes, int n_in,
                              void* d_out, int out_size, void* d_ws, size_t ws_size,
                              hipStream_t stream) {
    const float* x     = (const float*)d_in[0];
    const int*   ei    = (const int*)d_in[1];      // [2, E]: row0=src, row1=dst
    const float* W     = (const float*)d_in[2];
    const float* bvec  = (const float*)d_in[3];
    const float* gamma = (const float*)d_in[4];
    const float* beta  = (const float*)d_in[5];
    float* y = (float*)d_out;

    const int* src = ei;
    const int* dst = ei + N_EDGES;

    float* hp       = (float*)d_ws;                        // (N+1)*D (row N = zeros)
    float* dinv     = hp + (size_t)(N_NODES + 1) * D;      // N
    float* stats    = dinv + N_NODES;                      // 256
    int*   cnt      = (int*)(stats + 256);                 // N
    int*   rowstart = cnt + N_NODES;                       // N+1
    int*   cursor   = rowstart + N_NODES + 1;              // N
    int*   csr      = cursor + N_NODES;                    // E
    int*   bsum     = csr + N_EDGES;                       // 256
    int*   bbase    = bsum + 256;                          // 256

    k_init<<<SCAN_BLOCKS, 256, 0, stream>>>(cnt, stats, hp + (size_t)N_NODES * D);
    k_count<<<(N_EDGES + 255) / 256, 256, 0, stream>>>(dst, cnt);
    k_scanpart<<<SCAN_BLOCKS, 256, 0, stream>>>(cnt, bsum);
    k_scantop<<<1, 256, 0, stream>>>(bsum, bbase);
    k_scanfill<<<SCAN_BLOCKS, 256, 0, stream>>>(cnt, bbase, rowstart, cursor, dinv);
    k_fill<<<(N_EDGES + 255) / 256, 256, 0, stream>>>(src, dst, cursor, csr);
    k_gemm<<<N_NODES / 32, 256, 0, stream>>>(x, W, dinv, hp);
    k_gather<<<1667, 256, 0, stream>>>(hp, dinv, rowstart, csr, bvec, y, stats);
    k_bnfinal<<<(N_NODES * 32 + 255) / 256, 256, 0, stream>>>(y, stats, gamma, beta);
}

// Round 6
// 262.254 us; speedup vs baseline: 4.5977x; 1.1744x over previous
//
#include <hip/hip_runtime.h>
#include <math.h>

#define N_NODES 40000
#define N_EDGES 640000
#define D 128
#define BN_EPS 1e-5f
#define SCAN_BLOCKS ((N_NODES + 255) / 256)   // 157

// bf16 helpers (RNE pack, shift unpack)
__device__ __forceinline__ unsigned bfr(float f) {
    unsigned b = __float_as_uint(f);
    return (b + 0x7fffu + ((b >> 16) & 1u)) >> 16;
}
__device__ __forceinline__ float4 bf4(uint2 u) {
    float4 r;
    r.x = __uint_as_float(u.x << 16);
    r.y = __uint_as_float(u.x & 0xffff0000u);
    r.z = __uint_as_float(u.y << 16);
    r.w = __uint_as_float(u.y & 0xffff0000u);
    return r;
}

// ---------------- init: zero degree counts + BN stats + zero row ----------------

__global__ __launch_bounds__(256) void k_init(int* __restrict__ cnt,
                                              float* __restrict__ stats,
                                              unsigned* __restrict__ zrow) {
    int i = blockIdx.x * 256 + threadIdx.x;
    if (i < N_NODES) cnt[i] = 0;
    if (i < 256) stats[i] = 0.0f;
    if (i < 64) zrow[i] = 0u;      // bf16 row N_NODES = 128 bf16 = 64 uints
}

__global__ __launch_bounds__(256) void k_count(const int* __restrict__ dst,
                                               int* __restrict__ cnt) {
    int e = blockIdx.x * 256 + threadIdx.x;
    if (e < N_EDGES) atomicAdd(&cnt[dst[e]], 1);
}

// ---------------- parallel scan chain ----------------

__global__ __launch_bounds__(256) void k_scanpart(const int* __restrict__ cnt,
                                                  int* __restrict__ bsum) {
    __shared__ int red[256];
    int i = blockIdx.x * 256 + threadIdx.x;
    red[threadIdx.x] = (i < N_NODES) ? cnt[i] : 0;
    __syncthreads();
    for (int off = 128; off > 0; off >>= 1) {
        if (threadIdx.x < off) red[threadIdx.x] += red[threadIdx.x + off];
        __syncthreads();
    }
    if (threadIdx.x == 0) bsum[blockIdx.x] = red[0];
}

__global__ __launch_bounds__(256) void k_scantop(const int* __restrict__ bsum,
                                                 int* __restrict__ bbase) {
    __shared__ int part[256];
    int t = threadIdx.x;
    int v = (t < SCAN_BLOCKS) ? bsum[t] : 0;
    part[t] = v;
    __syncthreads();
    for (int off = 1; off < 256; off <<= 1) {
        int p = (t >= off) ? part[t - off] : 0;
        __syncthreads();
        part[t] += p;
        __syncthreads();
    }
    bbase[t] = part[t] - v;   // exclusive
}

__global__ __launch_bounds__(256) void k_scanfill(const int* __restrict__ cnt,
                                                  const int* __restrict__ bbase,
                                                  int* __restrict__ rowstart,
                                                  int* __restrict__ cursor,
                                                  float* __restrict__ dinv) {
    __shared__ int part[256];
    int t = threadIdx.x;
    int i = blockIdx.x * 256 + t;
    int c = (i < N_NODES) ? cnt[i] : 0;
    part[t] = c;
    __syncthreads();
    for (int off = 1; off < 256; off <<= 1) {
        int p = (t >= off) ? part[t - off] : 0;
        __syncthreads();
        part[t] += p;
        __syncthreads();
    }
    int rs = bbase[blockIdx.x] + part[t] - c;   // exclusive prefix
    if (i < N_NODES) {
        rowstart[i] = rs;
        cursor[i] = rs;
        dinv[i] = rsqrtf((float)(c + 1));       // +1 self-loop
        if (i == N_NODES - 1) rowstart[N_NODES] = rs + c;   // == N_EDGES
    }
}

__global__ __launch_bounds__(256) void k_fill(const int* __restrict__ src,
                                              const int* __restrict__ dst,
                                              int* __restrict__ cursor,
                                              int* __restrict__ csr) {
    int e = blockIdx.x * 256 + threadIdx.x;
    if (e < N_EDGES) {
        int pos = atomicAdd(&cursor[dst[e]], 1);
        csr[pos] = src[e];
    }
}

// ---------------- h' = (x @ W) * dinv[row], bf16 out ; 32 rows/block ----------------

__global__ __launch_bounds__(256) void k_gemm(const float* __restrict__ x,
                                              const float* __restrict__ W,
                                              const float* __restrict__ dinv,
                                              unsigned short* __restrict__ hp) {
    __shared__ float Ws[D * D];       // 64 KB
    __shared__ float xs[32 * D];      // 16 KB
    for (int i = threadIdx.x; i < D * D / 4; i += 256)
        ((float4*)Ws)[i] = ((const float4*)W)[i];
    int r0 = blockIdx.x * 32;
    for (int i = threadIdx.x; i < 32 * D / 4; i += 256)
        ((float4*)xs)[i] = ((const float4*)(x + (size_t)r0 * D))[i];
    __syncthreads();

    int c = threadIdx.x & 31;   // 4-col group
    int g = threadIdx.x >> 5;   // 4-row group
    const float4* Ws4 = (const float4*)Ws;
    float4 acc0 = {0,0,0,0}, acc1 = {0,0,0,0}, acc2 = {0,0,0,0}, acc3 = {0,0,0,0};
    const float4* xr0 = (const float4*)(xs + (g * 4 + 0) * D);
    const float4* xr1 = (const float4*)(xs + (g * 4 + 1) * D);
    const float4* xr2 = (const float4*)(xs + (g * 4 + 2) * D);
    const float4* xr3 = (const float4*)(xs + (g * 4 + 3) * D);
    for (int k4 = 0; k4 < D / 4; ++k4) {
        float4 a = xr0[k4], b = xr1[k4], cc = xr2[k4], d = xr3[k4];
        float xe0[4] = {a.x, a.y, a.z, a.w};
        float xe1[4] = {b.x, b.y, b.z, b.w};
        float xe2[4] = {cc.x, cc.y, cc.z, cc.w};
        float xe3[4] = {d.x, d.y, d.z, d.w};
#pragma unroll
        for (int j = 0; j < 4; ++j) {
            float4 w = Ws4[(k4 * 4 + j) * 32 + c];
            acc0.x = fmaf(xe0[j], w.x, acc0.x); acc0.y = fmaf(xe0[j], w.y, acc0.y);
            acc0.z = fmaf(xe0[j], w.z, acc0.z); acc0.w = fmaf(xe0[j], w.w, acc0.w);
            acc1.x = fmaf(xe1[j], w.x, acc1.x); acc1.y = fmaf(xe1[j], w.y, acc1.y);
            acc1.z = fmaf(xe1[j], w.z, acc1.z); acc1.w = fmaf(xe1[j], w.w, acc1.w);
            acc2.x = fmaf(xe2[j], w.x, acc2.x); acc2.y = fmaf(xe2[j], w.y, acc2.y);
            acc2.z = fmaf(xe2[j], w.z, acc2.z); acc2.w = fmaf(xe2[j], w.w, acc2.w);
            acc3.x = fmaf(xe3[j], w.x, acc3.x); acc3.y = fmaf(xe3[j], w.y, acc3.y);
            acc3.z = fmaf(xe3[j], w.z, acc3.z); acc3.w = fmaf(xe3[j], w.w, acc3.w);
        }
    }
    float4 a[4] = {acc0, acc1, acc2, acc3};
#pragma unroll
    for (int rr = 0; rr < 4; ++rr) {
        int r = r0 + g * 4 + rr;
        float sc = dinv[r];
        float4 v = a[rr];
        uint2 p;
        p.x = bfr(v.x * sc) | (bfr(v.y * sc) << 16);
        p.y = bfr(v.z * sc) | (bfr(v.w * sc) << 16);
        ((uint2*)hp)[(size_t)r * 32 + c] = p;
    }
}

// ---------------- gather: y[n] = relu((h'[n] + sum h'[s]) * dinv[n] + b)
//       bf16 rows, predicated 4-wide bursts, fused BN partials

__global__ __launch_bounds__(256) void k_gather(const unsigned short* __restrict__ hp,
                                                const float* __restrict__ dinv,
                                                const int* __restrict__ rowstart,
                                                const int* __restrict__ csr,
                                                const float* __restrict__ bvec,
                                                float* __restrict__ y,
                                                float* __restrict__ stats) {
    const uint2* h2 = (const uint2*)hp;
    float4* y4 = (float4*)y;
    int c = threadIdx.x & 31;   // 4-col group
    int g = threadIdx.x >> 5;   // node within group of 8
    float4 b4 = ((const float4*)bvec)[c];
    float4 sum = {0,0,0,0}, ssq = {0,0,0,0};

    const int NG = N_NODES / 8;   // 5000 groups; 1250 blocks x 4
    for (int grp = blockIdx.x; grp < NG; grp += gridDim.x) {
        int n = grp * 8 + g;
        float4 acc = bf4(h2[(size_t)n * 32 + c]);   // self-loop term
        int j0 = rowstart[n], j1 = rowstart[n + 1];
        for (int j = j0; j < j1; j += 4) {
            int i0, i1, i2, i3;
            {
                int m = j1 - 1;
                int s0 = csr[min(j + 0, m)], s1 = csr[min(j + 1, m)];
                int s2 = csr[min(j + 2, m)], s3 = csr[min(j + 3, m)];
                i0 = s0;                               // j < j1 always
                i1 = (j + 1 < j1) ? s1 : N_NODES;      // pad -> zero row
                i2 = (j + 2 < j1) ? s2 : N_NODES;
                i3 = (j + 3 < j1) ? s3 : N_NODES;
            }
            uint2 u0 = h2[(size_t)i0 * 32 + c];
            uint2 u1 = h2[(size_t)i1 * 32 + c];
            uint2 u2 = h2[(size_t)i2 * 32 + c];
            uint2 u3 = h2[(size_t)i3 * 32 + c];
            float4 v0 = bf4(u0), v1 = bf4(u1), v2 = bf4(u2), v3 = bf4(u3);
            acc.x += (v0.x + v1.x) + (v2.x + v3.x);
            acc.y += (v0.y + v1.y) + (v2.y + v3.y);
            acc.z += (v0.z + v1.z) + (v2.z + v3.z);
            acc.w += (v0.w + v1.w) + (v2.w + v3.w);
        }
        float di = dinv[n];
        float4 o;
        o.x = fmaxf(fmaf(acc.x, di, b4.x), 0.f);
        o.y = fmaxf(fmaf(acc.y, di, b4.y), 0.f);
        o.z = fmaxf(fmaf(acc.z, di, b4.z), 0.f);
        o.w = fmaxf(fmaf(acc.w, di, b4.w), 0.f);
        y4[(size_t)n * 32 + c] = o;
        sum.x += o.x; sum.y += o.y; sum.z += o.z; sum.w += o.w;
        ssq.x = fmaf(o.x, o.x, ssq.x); ssq.y = fmaf(o.y, o.y, ssq.y);
        ssq.z = fmaf(o.z, o.z, ssq.z); ssq.w = fmaf(o.w, o.w, ssq.w);
    }

    __shared__ float4 s1m[256], s2m[256];
    s1m[threadIdx.x] = sum;
    s2m[threadIdx.x] = ssq;
    __syncthreads();
    if (threadIdx.x < 32) {
        float4 a = s1m[threadIdx.x], b = s2m[threadIdx.x];
#pragma unroll
        for (int g2 = 1; g2 < 8; ++g2) {
            float4 p = s1m[g2 * 32 + threadIdx.x], q = s2m[g2 * 32 + threadIdx.x];
            a.x += p.x; a.y += p.y; a.z += p.z; a.w += p.w;
            b.x += q.x; b.y += q.y; b.z += q.z; b.w += q.w;
        }
        int d0 = 4 * threadIdx.x;
        atomicAdd(&stats[d0 + 0], a.x); atomicAdd(&stats[d0 + 1], a.y);
        atomicAdd(&stats[d0 + 2], a.z); atomicAdd(&stats[d0 + 3], a.w);
        atomicAdd(&stats[128 + d0 + 0], b.x); atomicAdd(&stats[128 + d0 + 1], b.y);
        atomicAdd(&stats[128 + d0 + 2], b.z); atomicAdd(&stats[128 + d0 + 3], b.w);
    }
}

// ---------------- BN finalize (in place on y) ----------------

__global__ __launch_bounds__(256) void k_bnfinal(float* __restrict__ y,
                                                 const float* __restrict__ stats,
                                                 const float* __restrict__ gamma,
                                                 const float* __restrict__ beta) {
    int idx = blockIdx.x * 256 + threadIdx.x;   // one float4 per thread
    if (idx < N_NODES * 32) {
        int c = idx & 31;
        float4 v = ((const float4*)y)[idx];
        float invN = 1.0f / (float)N_NODES;
        float o[4] = {v.x, v.y, v.z, v.w};
#pragma unroll
        for (int j = 0; j < 4; ++j) {
            int dd = 4 * c + j;
            float mean = stats[dd] * invN;
            float var = stats[128 + dd] * invN - mean * mean;
            float rs = rsqrtf(var + BN_EPS);
            o[j] = (o[j] - mean) * rs * gamma[dd] + beta[dd];
        }
        ((float4*)y)[idx] = make_float4(o[0], o[1], o[2], o[3]);
    }
}

extern "C" void kernel_launch(void* const* d_in, const int* in_sizes, int n_in,
                              void* d_out, int out_size, void* d_ws, size_t ws_size,
                              hipStream_t stream) {
    const float* x     = (const float*)d_in[0];
    const int*   ei    = (const int*)d_in[1];      // [2, E]: row0=src, row1=dst
    const float* W     = (const float*)d_in[2];
    const float* bvec  = (const float*)d_in[3];
    const float* gamma = (const float*)d_in[4];
    const float* beta  = (const float*)d_in[5];
    float* y = (float*)d_out;

    const int* src = ei;
    const int* dst = ei + N_EDGES;

    char* ws = (char*)d_ws;
    unsigned short* hp = (unsigned short*)ws;              // (N+1)*D bf16 (row N = 0)
    size_t hp_bytes = (size_t)(N_NODES + 1) * D * 2;
    float* dinv     = (float*)(ws + hp_bytes);             // N
    float* stats    = dinv + N_NODES;                      // 256
    int*   cnt      = (int*)(stats + 256);                 // N
    int*   rowstart = cnt + N_NODES;                       // N+1
    int*   cursor   = rowstart + N_NODES + 1;              // N
    int*   csr      = cursor + N_NODES;                    // E
    int*   bsum     = csr + N_EDGES;                       // 256
    int*   bbase    = bsum + 256;                          // 256

    k_init<<<SCAN_BLOCKS, 256, 0, stream>>>(cnt, stats,
                                            (unsigned*)(hp + (size_t)N_NODES * D));
    k_count<<<(N_EDGES + 255) / 256, 256, 0, stream>>>(dst, cnt);
    k_scanpart<<<SCAN_BLOCKS, 256, 0, stream>>>(cnt, bsum);
    k_scantop<<<1, 256, 0, stream>>>(bsum, bbase);
    k_scanfill<<<SCAN_BLOCKS, 256, 0, stream>>>(cnt, bbase, rowstart, cursor, dinv);
    k_fill<<<(N_EDGES + 255) / 256, 256, 0, stream>>>(src, dst, cursor, csr);
    k_gemm<<<N_NODES / 32, 256, 0, stream>>>(x, W, dinv, hp);
    k_gather<<<1250, 256, 0, stream>>>(hp, dinv, rowstart, csr, bvec, y, stats);
    k_bnfinal<<<(N_NODES * 32 + 255) / 256, 256, 0, stream>>>(y, stats, gamma, beta);
}

// Round 7
// 160.261 us; speedup vs baseline: 7.5238x; 1.6364x over previous
//
#include <hip/hip_runtime.h>
#include <math.h>

#define N_NODES 40000
#define N_EDGES 640000
#define D 128
#define BN_EPS 1e-5f
#define SCAN_BLOCKS ((N_NODES + 255) / 256)   // 157
#define PAD 4                                  // CSR segment padding granularity
#define PADMAX (N_EDGES + 3 * N_NODES)         // 760000 worst-case padded entries
#define NBUCKET 64

// bf16 helpers (RNE pack, shift unpack)
__device__ __forceinline__ unsigned bfr(float f) {
    unsigned b = __float_as_uint(f);
    return (b + 0x7fffu + ((b >> 16) & 1u)) >> 16;
}
__device__ __forceinline__ float4 bf4(uint2 u) {
    float4 r;
    r.x = __uint_as_float(u.x << 16);
    r.y = __uint_as_float(u.x & 0xffff0000u);
    r.z = __uint_as_float(u.y << 16);
    r.w = __uint_as_float(u.y & 0xffff0000u);
    return r;
}

// ---------------- init: cnt, stat buckets, zero row, csr pre-fill ----------------

__global__ __launch_bounds__(256) void k_init(int* __restrict__ cnt,
                                              float* __restrict__ smulti,
                                              unsigned* __restrict__ zrow,
                                              int* __restrict__ csr) {
    int i = blockIdx.x * 256 + threadIdx.x;
    int total = SCAN_BLOCKS * 256;
    if (i < N_NODES) cnt[i] = 0;
    for (int k = i; k < NBUCKET * 256; k += total) smulti[k] = 0.0f;
    if (i < 64) zrow[i] = 0u;      // bf16 row N_NODES = 128 bf16 = 64 uints
    for (int k = i; k < PADMAX; k += total) csr[k] = N_NODES;   // pad -> zero row
}

__global__ __launch_bounds__(256) void k_count(const int* __restrict__ dst,
                                               int* __restrict__ cnt) {
    int e = blockIdx.x * 256 + threadIdx.x;
    if (e < N_EDGES) atomicAdd(&cnt[dst[e]], 1);
}

// ---------------- parallel scan chain (over PADDED counts) ----------------

__global__ __launch_bounds__(256) void k_scanpart(const int* __restrict__ cnt,
                                                  int* __restrict__ bsum) {
    __shared__ int red[256];
    int i = blockIdx.x * 256 + threadIdx.x;
    int c = (i < N_NODES) ? cnt[i] : 0;
    red[threadIdx.x] = (c + (PAD - 1)) & ~(PAD - 1);
    __syncthreads();
    for (int off = 128; off > 0; off >>= 1) {
        if (threadIdx.x < off) red[threadIdx.x] += red[threadIdx.x + off];
        __syncthreads();
    }
    if (threadIdx.x == 0) bsum[blockIdx.x] = red[0];
}

__global__ __launch_bounds__(256) void k_scantop(const int* __restrict__ bsum,
                                                 int* __restrict__ bbase) {
    __shared__ int part[256];
    int t = threadIdx.x;
    int v = (t < SCAN_BLOCKS) ? bsum[t] : 0;
    part[t] = v;
    __syncthreads();
    for (int off = 1; off < 256; off <<= 1) {
        int p = (t >= off) ? part[t - off] : 0;
        __syncthreads();
        part[t] += p;
        __syncthreads();
    }
    bbase[t] = part[t] - v;   // exclusive
}

__global__ __launch_bounds__(256) void k_scanfill(const int* __restrict__ cnt,
                                                  const int* __restrict__ bbase,
                                                  int* __restrict__ rowstart,
                                                  int* __restrict__ cursor,
                                                  float* __restrict__ dinv) {
    __shared__ int part[256];
    int t = threadIdx.x;
    int i = blockIdx.x * 256 + t;
    int c = (i < N_NODES) ? cnt[i] : 0;
    int pc = (c + (PAD - 1)) & ~(PAD - 1);
    part[t] = pc;
    __syncthreads();
    for (int off = 1; off < 256; off <<= 1) {
        int p = (t >= off) ? part[t - off] : 0;
        __syncthreads();
        part[t] += p;
        __syncthreads();
    }
    int rs = bbase[blockIdx.x] + part[t] - pc;   // exclusive padded prefix
    if (i < N_NODES) {
        rowstart[i] = rs;
        cursor[i] = rs;
        dinv[i] = rsqrtf((float)(c + 1));        // +1 self-loop (true count)
        if (i == N_NODES - 1) rowstart[N_NODES] = rs + pc;
    }
}

__global__ __launch_bounds__(256) void k_fill(const int* __restrict__ src,
                                              const int* __restrict__ dst,
                                              int* __restrict__ cursor,
                                              int* __restrict__ csr) {
    int e = blockIdx.x * 256 + threadIdx.x;
    if (e < N_EDGES) {
        int pos = atomicAdd(&cursor[dst[e]], 1);
        csr[pos] = src[e];
    }
}

// ---------------- h' = (x @ W) * dinv[row], bf16 out ; 32 rows/block ----------------

__global__ __launch_bounds__(256) void k_gemm(const float* __restrict__ x,
                                              const float* __restrict__ W,
                                              const float* __restrict__ dinv,
                                              unsigned short* __restrict__ hp) {
    __shared__ float Ws[D * D];       // 64 KB
    __shared__ float xs[32 * D];      // 16 KB
    for (int i = threadIdx.x; i < D * D / 4; i += 256)
        ((float4*)Ws)[i] = ((const float4*)W)[i];
    int r0 = blockIdx.x * 32;
    for (int i = threadIdx.x; i < 32 * D / 4; i += 256)
        ((float4*)xs)[i] = ((const float4*)(x + (size_t)r0 * D))[i];
    __syncthreads();

    int c = threadIdx.x & 31;   // 4-col group
    int g = threadIdx.x >> 5;   // 4-row group
    const float4* Ws4 = (const float4*)Ws;
    float4 acc0 = {0,0,0,0}, acc1 = {0,0,0,0}, acc2 = {0,0,0,0}, acc3 = {0,0,0,0};
    const float4* xr0 = (const float4*)(xs + (g * 4 + 0) * D);
    const float4* xr1 = (const float4*)(xs + (g * 4 + 1) * D);
    const float4* xr2 = (const float4*)(xs + (g * 4 + 2) * D);
    const float4* xr3 = (const float4*)(xs + (g * 4 + 3) * D);
    for (int k4 = 0; k4 < D / 4; ++k4) {
        float4 a = xr0[k4], b = xr1[k4], cc = xr2[k4], d = xr3[k4];
        float xe0[4] = {a.x, a.y, a.z, a.w};
        float xe1[4] = {b.x, b.y, b.z, b.w};
        float xe2[4] = {cc.x, cc.y, cc.z, cc.w};
        float xe3[4] = {d.x, d.y, d.z, d.w};
#pragma unroll
        for (int j = 0; j < 4; ++j) {
            float4 w = Ws4[(k4 * 4 + j) * 32 + c];
            acc0.x = fmaf(xe0[j], w.x, acc0.x); acc0.y = fmaf(xe0[j], w.y, acc0.y);
            acc0.z = fmaf(xe0[j], w.z, acc0.z); acc0.w = fmaf(xe0[j], w.w, acc0.w);
            acc1.x = fmaf(xe1[j], w.x, acc1.x); acc1.y = fmaf(xe1[j], w.y, acc1.y);
            acc1.z = fmaf(xe1[j], w.z, acc1.z); acc1.w = fmaf(xe1[j], w.w, acc1.w);
            acc2.x = fmaf(xe2[j], w.x, acc2.x); acc2.y = fmaf(xe2[j], w.y, acc2.y);
            acc2.z = fmaf(xe2[j], w.z, acc2.z); acc2.w = fmaf(xe2[j], w.w, acc2.w);
            acc3.x = fmaf(xe3[j], w.x, acc3.x); acc3.y = fmaf(xe3[j], w.y, acc3.y);
            acc3.z = fmaf(xe3[j], w.z, acc3.z); acc3.w = fmaf(xe3[j], w.w, acc3.w);
        }
    }
    float4 a[4] = {acc0, acc1, acc2, acc3};
#pragma unroll
    for (int rr = 0; rr < 4; ++rr) {
        int r = r0 + g * 4 + rr;
        float sc = dinv[r];
        float4 v = a[rr];
        uint2 p;
        p.x = bfr(v.x * sc) | (bfr(v.y * sc) << 16);
        p.y = bfr(v.z * sc) | (bfr(v.w * sc) << 16);
        ((uint2*)hp)[(size_t)r * 32 + c] = p;
    }
}

// ---------------- gather: y[n] = relu((h'[n] + sum h'[s]) * dinv[n] + b)
//       padded CSR (no predication), 4-wide bursts, 1 group/block, 5000 blocks

__global__ __launch_bounds__(256) void k_gather(const unsigned short* __restrict__ hp,
                                                const float* __restrict__ dinv,
                                                const int* __restrict__ rowstart,
                                                const int* __restrict__ csr,
                                                const float* __restrict__ bvec,
                                                float* __restrict__ y,
                                                float* __restrict__ smulti) {
    const uint2* h2 = (const uint2*)hp;
    float4* y4 = (float4*)y;
    int c = threadIdx.x & 31;   // 4-col group
    int g = threadIdx.x >> 5;   // node within group of 8
    float4 b4 = ((const float4*)bvec)[c];

    int n = blockIdx.x * 8 + g;
    float4 acc = bf4(h2[(size_t)n * 32 + c]);   // self-loop term
    int j0 = rowstart[n], j1 = rowstart[n + 1];  // padded: (j1-j0) % 4 == 0
    for (int j = j0; j < j1; j += 4) {
        int s0 = csr[j + 0], s1 = csr[j + 1], s2 = csr[j + 2], s3 = csr[j + 3];
        uint2 u0 = h2[(size_t)s0 * 32 + c];
        uint2 u1 = h2[(size_t)s1 * 32 + c];
        uint2 u2 = h2[(size_t)s2 * 32 + c];
        uint2 u3 = h2[(size_t)s3 * 32 + c];
        float4 v0 = bf4(u0), v1 = bf4(u1), v2 = bf4(u2), v3 = bf4(u3);
        acc.x += (v0.x + v1.x) + (v2.x + v3.x);
        acc.y += (v0.y + v1.y) + (v2.y + v3.y);
        acc.z += (v0.z + v1.z) + (v2.z + v3.z);
        acc.w += (v0.w + v1.w) + (v2.w + v3.w);
    }
    float di = dinv[n];
    float4 o;
    o.x = fmaxf(fmaf(acc.x, di, b4.x), 0.f);
    o.y = fmaxf(fmaf(acc.y, di, b4.y), 0.f);
    o.z = fmaxf(fmaf(acc.z, di, b4.z), 0.f);
    o.w = fmaxf(fmaf(acc.w, di, b4.w), 0.f);
    y4[(size_t)n * 32 + c] = o;

    float4 sum = o;
    float4 ssq;
    ssq.x = o.x * o.x; ssq.y = o.y * o.y; ssq.z = o.z * o.z; ssq.w = o.w * o.w;

    __shared__ float4 s1m[256], s2m[256];
    s1m[threadIdx.x] = sum;
    s2m[threadIdx.x] = ssq;
    __syncthreads();
    if (threadIdx.x < 32) {
        float4 a = s1m[threadIdx.x], b = s2m[threadIdx.x];
#pragma unroll
        for (int g2 = 1; g2 < 8; ++g2) {
            float4 p = s1m[g2 * 32 + threadIdx.x], q = s2m[g2 * 32 + threadIdx.x];
            a.x += p.x; a.y += p.y; a.z += p.z; a.w += p.w;
            b.x += q.x; b.y += q.y; b.z += q.z; b.w += q.w;
        }
        float* sb = smulti + (blockIdx.x & (NBUCKET - 1)) * 256;
        int d0 = 4 * threadIdx.x;
        atomicAdd(&sb[d0 + 0], a.x); atomicAdd(&sb[d0 + 1], a.y);
        atomicAdd(&sb[d0 + 2], a.z); atomicAdd(&sb[d0 + 3], a.w);
        atomicAdd(&sb[128 + d0 + 0], b.x); atomicAdd(&sb[128 + d0 + 1], b.y);
        atomicAdd(&sb[128 + d0 + 2], b.z); atomicAdd(&sb[128 + d0 + 3], b.w);
    }
}

// ---------------- reduce 64 stat buckets -> stats[256] ----------------

__global__ __launch_bounds__(256) void k_bnred(const float* __restrict__ smulti,
                                               float* __restrict__ stats) {
    int t = threadIdx.x;
    float s = 0.f;
#pragma unroll 8
    for (int k = 0; k < NBUCKET; ++k) s += smulti[k * 256 + t];
    stats[t] = s;
}

// ---------------- BN finalize (in place on y) ----------------

__global__ __launch_bounds__(256) void k_bnfinal(float* __restrict__ y,
                                                 const float* __restrict__ stats,
                                                 const float* __restrict__ gamma,
                                                 const float* __restrict__ beta) {
    int idx = blockIdx.x * 256 + threadIdx.x;   // one float4 per thread
    if (idx < N_NODES * 32) {
        int c = idx & 31;
        float4 v = ((const float4*)y)[idx];
        float invN = 1.0f / (float)N_NODES;
        float o[4] = {v.x, v.y, v.z, v.w};
#pragma unroll
        for (int j = 0; j < 4; ++j) {
            int dd = 4 * c + j;
            float mean = stats[dd] * invN;
            float var = stats[128 + dd] * invN - mean * mean;
            float rs = rsqrtf(var + BN_EPS);
            o[j] = (o[j] - mean) * rs * gamma[dd] + beta[dd];
        }
        ((float4*)y)[idx] = make_float4(o[0], o[1], o[2], o[3]);
    }
}

extern "C" void kernel_launch(void* const* d_in, const int* in_sizes, int n_in,
                              void* d_out, int out_size, void* d_ws, size_t ws_size,
                              hipStream_t stream) {
    const float* x     = (const float*)d_in[0];
    const int*   ei    = (const int*)d_in[1];      // [2, E]: row0=src, row1=dst
    const float* W     = (const float*)d_in[2];
    const float* bvec  = (const float*)d_in[3];
    const float* gamma = (const float*)d_in[4];
    const float* beta  = (const float*)d_in[5];
    float* y = (float*)d_out;

    const int* src = ei;
    const int* dst = ei + N_EDGES;

    char* ws = (char*)d_ws;
    unsigned short* hp = (unsigned short*)ws;              // (N+1)*D bf16 (row N = 0)
    size_t hp_bytes = (size_t)(N_NODES + 1) * D * 2;
    float* dinv     = (float*)(ws + hp_bytes);             // N
    float* stats    = dinv + N_NODES;                      // 256
    float* smulti   = stats + 256;                         // 64*256
    int*   cnt      = (int*)(smulti + NBUCKET * 256);      // N
    int*   rowstart = cnt + N_NODES;                       // N+1
    int*   cursor   = rowstart + N_NODES + 1;              // N
    int*   csr      = cursor + N_NODES;                    // PADMAX
    int*   bsum     = csr + PADMAX;                        // 256
    int*   bbase    = bsum + 256;                          // 256

    k_init<<<SCAN_BLOCKS, 256, 0, stream>>>(cnt, smulti,
                                            (unsigned*)(hp + (size_t)N_NODES * D), csr);
    k_count<<<(N_EDGES + 255) / 256, 256, 0, stream>>>(dst, cnt);
    k_scanpart<<<SCAN_BLOCKS, 256, 0, stream>>>(cnt, bsum);
    k_scantop<<<1, 256, 0, stream>>>(bsum, bbase);
    k_scanfill<<<SCAN_BLOCKS, 256, 0, stream>>>(cnt, bbase, rowstart, cursor, dinv);
    k_fill<<<(N_EDGES + 255) / 256, 256, 0, stream>>>(src, dst, cursor, csr);
    k_gemm<<<N_NODES / 32, 256, 0, stream>>>(x, W, dinv, hp);
    k_gather<<<N_NODES / 8, 256, 0, stream>>>(hp, dinv, rowstart, csr, bvec, y, smulti);
    k_bnred<<<1, 256, 0, stream>>>(smulti, stats);
    k_bnfinal<<<(N_NODES * 32 + 255) / 256, 256, 0, stream>>>(y, stats, gamma, beta);
}

// Round 8
// 151.126 us; speedup vs baseline: 7.9785x; 1.0604x over previous
//
#include <hip/hip_runtime.h>
#include <math.h>

#define N_NODES 40000
#define N_EDGES 640000
#define D 128
#define BN_EPS 1e-5f
#define SCAN_BLOCKS ((N_NODES + 255) / 256)   // 157
#define PAD 4                                  // CSR segment padding granularity
#define PADMAX (N_EDGES + 3 * N_NODES)         // 760000 worst-case padded entries
#define NBUCKET 64

typedef __bf16 bf16x8 __attribute__((ext_vector_type(8)));
typedef unsigned short ushort8v __attribute__((ext_vector_type(8)));
typedef float floatx4 __attribute__((ext_vector_type(4)));

// bf16 helpers (RNE pack, shift unpack)
__device__ __forceinline__ unsigned bfr(float f) {
    unsigned b = __float_as_uint(f);
    return (b + 0x7fffu + ((b >> 16) & 1u)) >> 16;
}
__device__ __forceinline__ float4 bf4(uint2 u) {
    float4 r;
    r.x = __uint_as_float(u.x << 16);
    r.y = __uint_as_float(u.x & 0xffff0000u);
    r.z = __uint_as_float(u.y << 16);
    r.w = __uint_as_float(u.y & 0xffff0000u);
    return r;
}

// ---------------- init: cnt, stat buckets, zero row, csr pre-fill ----------------

__global__ __launch_bounds__(256) void k_init(int* __restrict__ cnt,
                                              float* __restrict__ smulti,
                                              unsigned* __restrict__ zrow,
                                              int* __restrict__ csr) {
    int i = blockIdx.x * 256 + threadIdx.x;
    int total = SCAN_BLOCKS * 256;
    if (i < N_NODES) cnt[i] = 0;
    for (int k = i; k < NBUCKET * 256; k += total) smulti[k] = 0.0f;
    if (i < 64) zrow[i] = 0u;      // bf16 row N_NODES = 128 bf16 = 64 uints
    for (int k = i; k < PADMAX; k += total) csr[k] = N_NODES;   // pad -> zero row
}

__global__ __launch_bounds__(256) void k_count(const int* __restrict__ dst,
                                               int* __restrict__ cnt) {
    int e = blockIdx.x * 256 + threadIdx.x;
    if (e < N_EDGES) atomicAdd(&cnt[dst[e]], 1);
}

// ---------------- Wt[c][k] = bf16(W[k][c]) ----------------

__global__ __launch_bounds__(256) void k_wt(const float* __restrict__ W,
                                            unsigned short* __restrict__ Wt) {
    int i = blockIdx.x * 256 + threadIdx.x;   // i = k*128 + c (coalesced read)
    if (i < D * D) {
        int k = i >> 7, c = i & 127;
        Wt[c * D + k] = (unsigned short)bfr(W[i]);
    }
}

// ---------------- parallel scan chain (over PADDED counts) ----------------

__global__ __launch_bounds__(256) void k_scanpart(const int* __restrict__ cnt,
                                                  int* __restrict__ bsum) {
    __shared__ int red[256];
    int i = blockIdx.x * 256 + threadIdx.x;
    int c = (i < N_NODES) ? cnt[i] : 0;
    red[threadIdx.x] = (c + (PAD - 1)) & ~(PAD - 1);
    __syncthreads();
    for (int off = 128; off > 0; off >>= 1) {
        if (threadIdx.x < off) red[threadIdx.x] += red[threadIdx.x + off];
        __syncthreads();
    }
    if (threadIdx.x == 0) bsum[blockIdx.x] = red[0];
}

__global__ __launch_bounds__(256) void k_scantop(const int* __restrict__ bsum,
                                                 int* __restrict__ bbase) {
    __shared__ int part[256];
    int t = threadIdx.x;
    int v = (t < SCAN_BLOCKS) ? bsum[t] : 0;
    part[t] = v;
    __syncthreads();
    for (int off = 1; off < 256; off <<= 1) {
        int p = (t >= off) ? part[t - off] : 0;
        __syncthreads();
        part[t] += p;
        __syncthreads();
    }
    bbase[t] = part[t] - v;   // exclusive
}

__global__ __launch_bounds__(256) void k_scanfill(const int* __restrict__ cnt,
                                                  const int* __restrict__ bbase,
                                                  int* __restrict__ rowstart,
                                                  int* __restrict__ cursor,
                                                  float* __restrict__ dinv) {
    __shared__ int part[256];
    int t = threadIdx.x;
    int i = blockIdx.x * 256 + t;
    int c = (i < N_NODES) ? cnt[i] : 0;
    int pc = (c + (PAD - 1)) & ~(PAD - 1);
    part[t] = pc;
    __syncthreads();
    for (int off = 1; off < 256; off <<= 1) {
        int p = (t >= off) ? part[t - off] : 0;
        __syncthreads();
        part[t] += p;
        __syncthreads();
    }
    int rs = bbase[blockIdx.x] + part[t] - pc;   // exclusive padded prefix
    if (i < N_NODES) {
        rowstart[i] = rs;
        cursor[i] = rs;
        dinv[i] = rsqrtf((float)(c + 1));        // +1 self-loop (true count)
        if (i == N_NODES - 1) rowstart[N_NODES] = rs + pc;
    }
}

__global__ __launch_bounds__(256) void k_fill(const int* __restrict__ src,
                                              const int* __restrict__ dst,
                                              int* __restrict__ cursor,
                                              int* __restrict__ csr) {
    int e = blockIdx.x * 256 + threadIdx.x;
    if (e < N_EDGES) {
        int pos = atomicAdd(&cursor[dst[e]], 1);
        csr[pos] = src[e];
    }
}

// ---------------- MFMA GEMM: hp[r][c] = bf16((x @ W)[r][c] * dinv[r]) ----------------
// 256 thr = 4 waves; wave w -> rows r0+16w..+15; 8 n-tiles x 4 k-steps of 16x16x32.
// A: x rows, f32 -> bf16 in regs (lane: m=lane&15, k=(lane>>4)*8+b).
// B: Wt rows (= W cols), 16B vector loads, L1/L2-hot.
// D: col=lane&15, row=(lane>>4)*4+reg (m89-verified).

__global__ __launch_bounds__(256) void k_gemm(const float* __restrict__ x,
                                              const unsigned short* __restrict__ Wt,
                                              const float* __restrict__ dinv,
                                              unsigned short* __restrict__ hp) {
    int wave = threadIdx.x >> 6;
    int lane = threadIdx.x & 63;
    int lm = lane & 15;
    int lg = lane >> 4;               // k-group / row-group
    int r0 = blockIdx.x * 64 + wave * 16;

    // A fragments: 4 k-steps x 8 bf16
    bf16x8 a[4];
    const float* xrow = x + (size_t)(r0 + lm) * D;
#pragma unroll
    for (int ks = 0; ks < 4; ++ks) {
        int k0 = ks * 32 + lg * 8;
        float4 u0 = *(const float4*)(xrow + k0);
        float4 u1 = *(const float4*)(xrow + k0 + 4);
        ushort8v av;
        av[0] = (unsigned short)bfr(u0.x); av[1] = (unsigned short)bfr(u0.y);
        av[2] = (unsigned short)bfr(u0.z); av[3] = (unsigned short)bfr(u0.w);
        av[4] = (unsigned short)bfr(u1.x); av[5] = (unsigned short)bfr(u1.y);
        av[6] = (unsigned short)bfr(u1.z); av[7] = (unsigned short)bfr(u1.w);
        a[ks] = __builtin_bit_cast(bf16x8, av);
    }
    // dinv for the 4 rows this lane writes
    float dv[4];
#pragma unroll
    for (int j = 0; j < 4; ++j) dv[j] = dinv[r0 + lg * 4 + j];

#pragma unroll
    for (int nt = 0; nt < 8; ++nt) {
        floatx4 acc = {0.f, 0.f, 0.f, 0.f};
        const unsigned short* wrow = Wt + (size_t)(nt * 16 + lm) * D;
#pragma unroll
        for (int ks = 0; ks < 4; ++ks) {
            int k0 = ks * 32 + lg * 8;
            bf16x8 b = __builtin_bit_cast(bf16x8, *(const ushort8v*)(wrow + k0));
            acc = __builtin_amdgcn_mfma_f32_16x16x32_bf16(a[ks], b, acc, 0, 0, 0);
        }
#pragma unroll
        for (int j = 0; j < 4; ++j) {
            int r = r0 + lg * 4 + j;
            hp[(size_t)r * D + nt * 16 + lm] = (unsigned short)bfr(acc[j] * dv[j]);
        }
    }
}

// ---------------- gather: y[n] = relu((h'[n] + sum h'[s]) * dinv[n] + b)
//       padded CSR (no predication), 4-wide bursts, 1 group/block, 5000 blocks

__global__ __launch_bounds__(256) void k_gather(const unsigned short* __restrict__ hp,
                                                const float* __restrict__ dinv,
                                                const int* __restrict__ rowstart,
                                                const int* __restrict__ csr,
                                                const float* __restrict__ bvec,
                                                float* __restrict__ y,
                                                float* __restrict__ smulti) {
    const uint2* h2 = (const uint2*)hp;
    float4* y4 = (float4*)y;
    int c = threadIdx.x & 31;   // 4-col group
    int g = threadIdx.x >> 5;   // node within group of 8
    float4 b4 = ((const float4*)bvec)[c];

    int n = blockIdx.x * 8 + g;
    float4 acc = bf4(h2[(size_t)n * 32 + c]);   // self-loop term
    int j0 = rowstart[n], j1 = rowstart[n + 1];  // padded: (j1-j0) % 4 == 0
    for (int j = j0; j < j1; j += 4) {
        int s0 = csr[j + 0], s1 = csr[j + 1], s2 = csr[j + 2], s3 = csr[j + 3];
        uint2 u0 = h2[(size_t)s0 * 32 + c];
        uint2 u1 = h2[(size_t)s1 * 32 + c];
        uint2 u2 = h2[(size_t)s2 * 32 + c];
        uint2 u3 = h2[(size_t)s3 * 32 + c];
        float4 v0 = bf4(u0), v1 = bf4(u1), v2 = bf4(u2), v3 = bf4(u3);
        acc.x += (v0.x + v1.x) + (v2.x + v3.x);
        acc.y += (v0.y + v1.y) + (v2.y + v3.y);
        acc.z += (v0.z + v1.z) + (v2.z + v3.z);
        acc.w += (v0.w + v1.w) + (v2.w + v3.w);
    }
    float di = dinv[n];
    float4 o;
    o.x = fmaxf(fmaf(acc.x, di, b4.x), 0.f);
    o.y = fmaxf(fmaf(acc.y, di, b4.y), 0.f);
    o.z = fmaxf(fmaf(acc.z, di, b4.z), 0.f);
    o.w = fmaxf(fmaf(acc.w, di, b4.w), 0.f);
    y4[(size_t)n * 32 + c] = o;

    float4 sum = o;
    float4 ssq;
    ssq.x = o.x * o.x; ssq.y = o.y * o.y; ssq.z = o.z * o.z; ssq.w = o.w * o.w;

    __shared__ float4 s1m[256], s2m[256];
    s1m[threadIdx.x] = sum;
    s2m[threadIdx.x] = ssq;
    __syncthreads();
    if (threadIdx.x < 32) {
        float4 a = s1m[threadIdx.x], b = s2m[threadIdx.x];
#pragma unroll
        for (int g2 = 1; g2 < 8; ++g2) {
            float4 p = s1m[g2 * 32 + threadIdx.x], q = s2m[g2 * 32 + threadIdx.x];
            a.x += p.x; a.y += p.y; a.z += p.z; a.w += p.w;
            b.x += q.x; b.y += q.y; b.z += q.z; b.w += q.w;
        }
        float* sb = smulti + (blockIdx.x & (NBUCKET - 1)) * 256;
        int d0 = 4 * threadIdx.x;
        atomicAdd(&sb[d0 + 0], a.x); atomicAdd(&sb[d0 + 1], a.y);
        atomicAdd(&sb[d0 + 2], a.z); atomicAdd(&sb[d0 + 3], a.w);
        atomicAdd(&sb[128 + d0 + 0], b.x); atomicAdd(&sb[128 + d0 + 1], b.y);
        atomicAdd(&sb[128 + d0 + 2], b.z); atomicAdd(&sb[128 + d0 + 3], b.w);
    }
}

// ---------------- reduce 64 stat buckets -> stats[256] ----------------

__global__ __launch_bounds__(256) void k_bnred(const float* __restrict__ smulti,
                                               float* __restrict__ stats) {
    int t = threadIdx.x;
    float s = 0.f;
#pragma unroll 8
    for (int k = 0; k < NBUCKET; ++k) s += smulti[k * 256 + t];
    stats[t] = s;
}

// ---------------- BN finalize (in place on y) ----------------

__global__ __launch_bounds__(256) void k_bnfinal(float* __restrict__ y,
                                                 const float* __restrict__ stats,
                                                 const float* __restrict__ gamma,
                                                 const float* __restrict__ beta) {
    int idx = blockIdx.x * 256 + threadIdx.x;   // one float4 per thread
    if (idx < N_NODES * 32) {
        int c = idx & 31;
        float4 v = ((const float4*)y)[idx];
        float invN = 1.0f / (float)N_NODES;
        float o[4] = {v.x, v.y, v.z, v.w};
#pragma unroll
        for (int j = 0; j < 4; ++j) {
            int dd = 4 * c + j;
            float mean = stats[dd] * invN;
            float var = stats[128 + dd] * invN - mean * mean;
            float rs = rsqrtf(var + BN_EPS);
            o[j] = (o[j] - mean) * rs * gamma[dd] + beta[dd];
        }
        ((float4*)y)[idx] = make_float4(o[0], o[1], o[2], o[3]);
    }
}

extern "C" void kernel_launch(void* const* d_in, const int* in_sizes, int n_in,
                              void* d_out, int out_size, void* d_ws, size_t ws_size,
                              hipStream_t stream) {
    const float* x     = (const float*)d_in[0];
    const int*   ei    = (const int*)d_in[1];      // [2, E]: row0=src, row1=dst
    const float* W     = (const float*)d_in[2];
    const float* bvec  = (const float*)d_in[3];
    const float* gamma = (const float*)d_in[4];
    const float* beta  = (const float*)d_in[5];
    float* y = (float*)d_out;

    const int* src = ei;
    const int* dst = ei + N_EDGES;

    char* ws = (char*)d_ws;
    unsigned short* hp = (unsigned short*)ws;              // (N+1)*D bf16 (row N = 0)
    size_t hp_bytes = (size_t)(N_NODES + 1) * D * 2;       // 16B-aligned
    unsigned short* Wt = (unsigned short*)(ws + hp_bytes); // 128*128 bf16
    float* dinv     = (float*)(ws + hp_bytes + D * D * 2); // N
    float* stats    = dinv + N_NODES;                      // 256
    float* smulti   = stats + 256;                         // 64*256
    int*   cnt      = (int*)(smulti + NBUCKET * 256);      // N
    int*   rowstart = cnt + N_NODES;                       // N+1
    int*   cursor   = rowstart + N_NODES + 1;              // N
    int*   csr      = cursor + N_NODES;                    // PADMAX
    int*   bsum     = csr + PADMAX;                        // 256
    int*   bbase    = bsum + 256;                          // 256

    k_init<<<SCAN_BLOCKS, 256, 0, stream>>>(cnt, smulti,
                                            (unsigned*)(hp + (size_t)N_NODES * D), csr);
    k_count<<<(N_EDGES + 255) / 256, 256, 0, stream>>>(dst, cnt);
    k_wt<<<(D * D + 255) / 256, 256, 0, stream>>>(W, Wt);
    k_scanpart<<<SCAN_BLOCKS, 256, 0, stream>>>(cnt, bsum);
    k_scantop<<<1, 256, 0, stream>>>(bsum, bbase);
    k_scanfill<<<SCAN_BLOCKS, 256, 0, stream>>>(cnt, bbase, rowstart, cursor, dinv);
    k_fill<<<(N_EDGES + 255) / 256, 256, 0, stream>>>(src, dst, cursor, csr);
    k_gemm<<<N_NODES / 64, 256, 0, stream>>>(x, Wt, dinv, hp);
    k_gather<<<N_NODES / 8, 256, 0, stream>>>(hp, dinv, rowstart, csr, bvec, y, smulti);
    k_bnred<<<1, 256, 0, stream>>>(smulti, stats);
    k_bnfinal<<<(N_NODES * 32 + 255) / 256, 256, 0, stream>>>(y, stats, gamma, beta);
}

// Round 9
// 144.109 us; speedup vs baseline: 8.3671x; 1.0487x over previous
//
#include <hip/hip_runtime.h>
#include <math.h>

#define N_NODES 40000
#define N_EDGES 640000
#define D 128
#define BN_EPS 1e-5f
#define SCAN_BLOCKS ((N_NODES + 255) / 256)   // 157
#define PAD 8                                  // CSR segment padding granularity
#define PADMAX (N_EDGES + 7 * N_NODES)         // 920000 worst-case padded entries
#define NBUCKET 64

typedef __bf16 bf16x8 __attribute__((ext_vector_type(8)));
typedef unsigned short ushort8v __attribute__((ext_vector_type(8)));
typedef float floatx4 __attribute__((ext_vector_type(4)));

// bf16 helpers (RNE pack, shift unpack)
__device__ __forceinline__ unsigned bfr(float f) {
    unsigned b = __float_as_uint(f);
    return (b + 0x7fffu + ((b >> 16) & 1u)) >> 16;
}
__device__ __forceinline__ float4 bf4(uint2 u) {
    float4 r;
    r.x = __uint_as_float(u.x << 16);
    r.y = __uint_as_float(u.x & 0xffff0000u);
    r.z = __uint_as_float(u.y << 16);
    r.w = __uint_as_float(u.y & 0xffff0000u);
    return r;
}

// ---------------- init: cnt, stat buckets, zero row, csr pre-fill, Wt ----------------

__global__ __launch_bounds__(256) void k_init(int* __restrict__ cnt,
                                              float* __restrict__ smulti,
                                              unsigned* __restrict__ zrow,
                                              int* __restrict__ csr,
                                              const float* __restrict__ W,
                                              unsigned short* __restrict__ Wt) {
    int i = blockIdx.x * 256 + threadIdx.x;
    int total = SCAN_BLOCKS * 256;
    if (i < N_NODES) cnt[i] = 0;
    for (int k = i; k < NBUCKET * 256; k += total) smulti[k] = 0.0f;
    if (i < 64) zrow[i] = 0u;      // bf16 row N_NODES = 128 bf16 = 64 uints
    for (int k = i; k < PADMAX; k += total) csr[k] = N_NODES;   // pad -> zero row
    if (i < D * D) {               // Wt[c][k] = bf16(W[k][c])
        int k = i >> 7, c = i & 127;
        Wt[c * D + k] = (unsigned short)bfr(W[i]);
    }
}

__global__ __launch_bounds__(256) void k_count(const int* __restrict__ dst,
                                               int* __restrict__ cnt) {
    int e = blockIdx.x * 256 + threadIdx.x;
    if (e < N_EDGES) atomicAdd(&cnt[dst[e]], 1);
}

// ---------------- parallel scan chain (over PADDED counts) ----------------

__global__ __launch_bounds__(256) void k_scanpart(const int* __restrict__ cnt,
                                                  int* __restrict__ bsum) {
    __shared__ int red[256];
    int i = blockIdx.x * 256 + threadIdx.x;
    int c = (i < N_NODES) ? cnt[i] : 0;
    red[threadIdx.x] = (c + (PAD - 1)) & ~(PAD - 1);
    __syncthreads();
    for (int off = 128; off > 0; off >>= 1) {
        if (threadIdx.x < off) red[threadIdx.x] += red[threadIdx.x + off];
        __syncthreads();
    }
    if (threadIdx.x == 0) bsum[blockIdx.x] = red[0];
}

__global__ __launch_bounds__(256) void k_scantop(const int* __restrict__ bsum,
                                                 int* __restrict__ bbase) {
    __shared__ int part[256];
    int t = threadIdx.x;
    int v = (t < SCAN_BLOCKS) ? bsum[t] : 0;
    part[t] = v;
    __syncthreads();
    for (int off = 1; off < 256; off <<= 1) {
        int p = (t >= off) ? part[t - off] : 0;
        __syncthreads();
        part[t] += p;
        __syncthreads();
    }
    bbase[t] = part[t] - v;   // exclusive
}

__global__ __launch_bounds__(256) void k_scanfill(const int* __restrict__ cnt,
                                                  const int* __restrict__ bbase,
                                                  int* __restrict__ rowstart,
                                                  int* __restrict__ cursor,
                                                  float* __restrict__ dinv) {
    __shared__ int part[256];
    int t = threadIdx.x;
    int i = blockIdx.x * 256 + t;
    int c = (i < N_NODES) ? cnt[i] : 0;
    int pc = (c + (PAD - 1)) & ~(PAD - 1);
    part[t] = pc;
    __syncthreads();
    for (int off = 1; off < 256; off <<= 1) {
        int p = (t >= off) ? part[t - off] : 0;
        __syncthreads();
        part[t] += p;
        __syncthreads();
    }
    int rs = bbase[blockIdx.x] + part[t] - pc;   // exclusive padded prefix
    if (i < N_NODES) {
        rowstart[i] = rs;
        cursor[i] = rs;
        dinv[i] = rsqrtf((float)(c + 1));        // +1 self-loop (true count)
        if (i == N_NODES - 1) rowstart[N_NODES] = rs + pc;
    }
}

__global__ __launch_bounds__(256) void k_fill(const int* __restrict__ src,
                                              const int* __restrict__ dst,
                                              int* __restrict__ cursor,
                                              int* __restrict__ csr) {
    int e = blockIdx.x * 256 + threadIdx.x;
    if (e < N_EDGES) {
        int pos = atomicAdd(&cursor[dst[e]], 1);
        csr[pos] = src[e];
    }
}

// ---------------- MFMA GEMM: hp[r][c] = bf16((x @ W)[r][c] * dinv[r]) ----------------
// 256 thr = 4 waves; wave w -> rows r0+16w..+15; 8 n-tiles x 4 k-steps of 16x16x32.
// Epilogue: bf16 tile staged in LDS, then coalesced uint4 stores (fixes the
// 32x 2-byte scattered global stores that dominated round 8's gemm).

__global__ __launch_bounds__(256) void k_gemm(const float* __restrict__ x,
                                              const unsigned short* __restrict__ Wt,
                                              const float* __restrict__ dinv,
                                              unsigned short* __restrict__ hp) {
    __shared__ unsigned short hs[64 * D];   // 16 KB
    int wave = threadIdx.x >> 6;
    int lane = threadIdx.x & 63;
    int lm = lane & 15;
    int lg = lane >> 4;               // k-group / row-group
    int r0 = blockIdx.x * 64 + wave * 16;

    // A fragments: 4 k-steps x 8 bf16
    bf16x8 a[4];
    const float* xrow = x + (size_t)(r0 + lm) * D;
#pragma unroll
    for (int ks = 0; ks < 4; ++ks) {
        int k0 = ks * 32 + lg * 8;
        float4 u0 = *(const float4*)(xrow + k0);
        float4 u1 = *(const float4*)(xrow + k0 + 4);
        ushort8v av;
        av[0] = (unsigned short)bfr(u0.x); av[1] = (unsigned short)bfr(u0.y);
        av[2] = (unsigned short)bfr(u0.z); av[3] = (unsigned short)bfr(u0.w);
        av[4] = (unsigned short)bfr(u1.x); av[5] = (unsigned short)bfr(u1.y);
        av[6] = (unsigned short)bfr(u1.z); av[7] = (unsigned short)bfr(u1.w);
        a[ks] = __builtin_bit_cast(bf16x8, av);
    }
    float dv[4];
#pragma unroll
    for (int j = 0; j < 4; ++j) dv[j] = dinv[r0 + lg * 4 + j];

#pragma unroll
    for (int nt = 0; nt < 8; ++nt) {
        floatx4 acc = {0.f, 0.f, 0.f, 0.f};
        const unsigned short* wrow = Wt + (size_t)(nt * 16 + lm) * D;
#pragma unroll
        for (int ks = 0; ks < 4; ++ks) {
            int k0 = ks * 32 + lg * 8;
            bf16x8 b = __builtin_bit_cast(bf16x8, *(const ushort8v*)(wrow + k0));
            acc = __builtin_amdgcn_mfma_f32_16x16x32_bf16(a[ks], b, acc, 0, 0, 0);
        }
#pragma unroll
        for (int j = 0; j < 4; ++j)
            hs[(wave * 16 + lg * 4 + j) * D + nt * 16 + lm] =
                (unsigned short)bfr(acc[j] * dv[j]);
    }
    __syncthreads();
    // coalesced store: 64 rows x 128 bf16 = 1024 uint4; 4 per thread
    const uint4* hs4 = (const uint4*)hs;
    uint4* out4 = (uint4*)(hp + (size_t)blockIdx.x * 64 * D);
#pragma unroll
    for (int i = 0; i < 4; ++i)
        out4[i * 256 + threadIdx.x] = hs4[i * 256 + threadIdx.x];
}

// ---------------- gather: y[n] = relu((h'[n] + sum h'[s]) * dinv[n] + b)
//       padded CSR (no predication), 8-wide bursts, 1 group/block, 5000 blocks

__global__ __launch_bounds__(256) void k_gather(const unsigned short* __restrict__ hp,
                                                const float* __restrict__ dinv,
                                                const int* __restrict__ rowstart,
                                                const int* __restrict__ csr,
                                                const float* __restrict__ bvec,
                                                float* __restrict__ y,
                                                float* __restrict__ smulti) {
    const uint2* h2 = (const uint2*)hp;
    float4* y4 = (float4*)y;
    int c = threadIdx.x & 31;   // 4-col group
    int g = threadIdx.x >> 5;   // node within group of 8
    float4 b4 = ((const float4*)bvec)[c];

    int n = blockIdx.x * 8 + g;
    float4 acc = bf4(h2[(size_t)n * 32 + c]);   // self-loop term
    int j0 = rowstart[n], j1 = rowstart[n + 1];  // padded: (j1-j0) % 8 == 0
    for (int j = j0; j < j1; j += 8) {
        int s0 = csr[j + 0], s1 = csr[j + 1], s2 = csr[j + 2], s3 = csr[j + 3];
        int s4 = csr[j + 4], s5 = csr[j + 5], s6 = csr[j + 6], s7 = csr[j + 7];
        uint2 u0 = h2[(size_t)s0 * 32 + c];
        uint2 u1 = h2[(size_t)s1 * 32 + c];
        uint2 u2 = h2[(size_t)s2 * 32 + c];
        uint2 u3 = h2[(size_t)s3 * 32 + c];
        uint2 u4 = h2[(size_t)s4 * 32 + c];
        uint2 u5 = h2[(size_t)s5 * 32 + c];
        uint2 u6 = h2[(size_t)s6 * 32 + c];
        uint2 u7 = h2[(size_t)s7 * 32 + c];
        float4 v0 = bf4(u0), v1 = bf4(u1), v2 = bf4(u2), v3 = bf4(u3);
        float4 v4 = bf4(u4), v5 = bf4(u5), v6 = bf4(u6), v7 = bf4(u7);
        acc.x += ((v0.x + v1.x) + (v2.x + v3.x)) + ((v4.x + v5.x) + (v6.x + v7.x));
        acc.y += ((v0.y + v1.y) + (v2.y + v3.y)) + ((v4.y + v5.y) + (v6.y + v7.y));
        acc.z += ((v0.z + v1.z) + (v2.z + v3.z)) + ((v4.z + v5.z) + (v6.z + v7.z));
        acc.w += ((v0.w + v1.w) + (v2.w + v3.w)) + ((v4.w + v5.w) + (v6.w + v7.w));
    }
    float di = dinv[n];
    float4 o;
    o.x = fmaxf(fmaf(acc.x, di, b4.x), 0.f);
    o.y = fmaxf(fmaf(acc.y, di, b4.y), 0.f);
    o.z = fmaxf(fmaf(acc.z, di, b4.z), 0.f);
    o.w = fmaxf(fmaf(acc.w, di, b4.w), 0.f);
    y4[(size_t)n * 32 + c] = o;

    float4 sum = o;
    float4 ssq;
    ssq.x = o.x * o.x; ssq.y = o.y * o.y; ssq.z = o.z * o.z; ssq.w = o.w * o.w;

    __shared__ float4 s1m[256], s2m[256];
    s1m[threadIdx.x] = sum;
    s2m[threadIdx.x] = ssq;
    __syncthreads();
    if (threadIdx.x < 32) {
        float4 a = s1m[threadIdx.x], b = s2m[threadIdx.x];
#pragma unroll
        for (int g2 = 1; g2 < 8; ++g2) {
            float4 p = s1m[g2 * 32 + threadIdx.x], q = s2m[g2 * 32 + threadIdx.x];
            a.x += p.x; a.y += p.y; a.z += p.z; a.w += p.w;
            b.x += q.x; b.y += q.y; b.z += q.z; b.w += q.w;
        }
        float* sb = smulti + (blockIdx.x & (NBUCKET - 1)) * 256;
        int d0 = 4 * threadIdx.x;
        atomicAdd(&sb[d0 + 0], a.x); atomicAdd(&sb[d0 + 1], a.y);
        atomicAdd(&sb[d0 + 2], a.z); atomicAdd(&sb[d0 + 3], a.w);
        atomicAdd(&sb[128 + d0 + 0], b.x); atomicAdd(&sb[128 + d0 + 1], b.y);
        atomicAdd(&sb[128 + d0 + 2], b.z); atomicAdd(&sb[128 + d0 + 3], b.w);
    }
}

// ---------------- reduce 64 stat buckets -> stats[256] ----------------

__global__ __launch_bounds__(256) void k_bnred(const float* __restrict__ smulti,
                                               float* __restrict__ stats) {
    int t = threadIdx.x;
    float s = 0.f;
#pragma unroll 8
    for (int k = 0; k < NBUCKET; ++k) s += smulti[k * 256 + t];
    stats[t] = s;
}

// ---------------- BN finalize (in place on y) ----------------

__global__ __launch_bounds__(256) void k_bnfinal(float* __restrict__ y,
                                                 const float* __restrict__ stats,
                                                 const float* __restrict__ gamma,
                                                 const float* __restrict__ beta) {
    int idx = blockIdx.x * 256 + threadIdx.x;   // one float4 per thread
    if (idx < N_NODES * 32) {
        int c = idx & 31;
        float4 v = ((const float4*)y)[idx];
        float invN = 1.0f / (float)N_NODES;
        float o[4] = {v.x, v.y, v.z, v.w};
#pragma unroll
        for (int j = 0; j < 4; ++j) {
            int dd = 4 * c + j;
            float mean = stats[dd] * invN;
            float var = stats[128 + dd] * invN - mean * mean;
            float rs = rsqrtf(var + BN_EPS);
            o[j] = (o[j] - mean) * rs * gamma[dd] + beta[dd];
        }
        ((float4*)y)[idx] = make_float4(o[0], o[1], o[2], o[3]);
    }
}

extern "C" void kernel_launch(void* const* d_in, const int* in_sizes, int n_in,
                              void* d_out, int out_size, void* d_ws, size_t ws_size,
                              hipStream_t stream) {
    const float* x     = (const float*)d_in[0];
    const int*   ei    = (const int*)d_in[1];      // [2, E]: row0=src, row1=dst
    const float* W     = (const float*)d_in[2];
    const float* bvec  = (const float*)d_in[3];
    const float* gamma = (const float*)d_in[4];
    const float* beta  = (const float*)d_in[5];
    float* y = (float*)d_out;

    const int* src = ei;
    const int* dst = ei + N_EDGES;

    char* ws = (char*)d_ws;
    unsigned short* hp = (unsigned short*)ws;              // (N+1)*D bf16 (row N = 0)
    size_t hp_bytes = (size_t)(N_NODES + 1) * D * 2;       // 16B-aligned
    unsigned short* Wt = (unsigned short*)(ws + hp_bytes); // 128*128 bf16
    float* dinv     = (float*)(ws + hp_bytes + D * D * 2); // N
    float* stats    = dinv + N_NODES;                      // 256
    float* smulti   = stats + 256;                         // 64*256
    int*   cnt      = (int*)(smulti + NBUCKET * 256);      // N
    int*   rowstart = cnt + N_NODES;                       // N+1
    int*   cursor   = rowstart + N_NODES + 1;              // N
    int*   csr      = cursor + N_NODES;                    // PADMAX
    int*   bsum     = csr + PADMAX;                        // 256
    int*   bbase    = bsum + 256;                          // 256

    k_init<<<SCAN_BLOCKS, 256, 0, stream>>>(cnt, smulti,
                                            (unsigned*)(hp + (size_t)N_NODES * D),
                                            csr, W, Wt);
    k_count<<<(N_EDGES + 255) / 256, 256, 0, stream>>>(dst, cnt);
    k_scanpart<<<SCAN_BLOCKS, 256, 0, stream>>>(cnt, bsum);
    k_scantop<<<1, 256, 0, stream>>>(bsum, bbase);
    k_scanfill<<<SCAN_BLOCKS, 256, 0, stream>>>(cnt, bbase, rowstart, cursor, dinv);
    k_fill<<<(N_EDGES + 255) / 256, 256, 0, stream>>>(src, dst, cursor, csr);
    k_gemm<<<N_NODES / 64, 256, 0, stream>>>(x, Wt, dinv, hp);
    k_gather<<<N_NODES / 8, 256, 0, stream>>>(hp, dinv, rowstart, csr, bvec, y, smulti);
    k_bnred<<<1, 256, 0, stream>>>(smulti, stats);
    k_bnfinal<<<(N_NODES * 32 + 255) / 256, 256, 0, stream>>>(y, stats, gamma, beta);
}